// Round 2
// baseline (2094.773 us; speedup 1.0000x reference)
//
#include <hip/hip_runtime.h>
#include <stdint.h>

#define D_    256
#define NH_   8
#define HD_   32
#define LV_   21760
#define DFF_  1024
#define EPS_  1e-5f

#define DOT4(XP, W) ((XP)[0]*(W).x + (XP)[1]*(W).y + (XP)[2]*(W).z + (XP)[3]*(W).w)

// ---------------- K1: value projection: v[b,h,l,hd] = src[b,l,:] @ vpw[h*32+hd,:] + vpb ----------
__global__ __launch_bounds__(256) void k_vproj(
        const float* __restrict__ src, const float* __restrict__ vpw,
        const float* __restrict__ vpb, float* __restrict__ vout) {
    __shared__ float X[16][D_];
    const int t = threadIdx.x;
    const long gr0 = (long)blockIdx.x * 16;
    const float4* sp = (const float4*)(src + gr0 * D_);
    #pragma unroll
    for (int i = 0; i < 4; ++i) {
        int ii = t + i * 256;                 // 1024 float4 = 16 rows x 256
        float4 v = sp[ii];
        int r = ii >> 6, d0 = (ii & 63) << 2;
        X[r][d0] = v.x; X[r][d0+1] = v.y; X[r][d0+2] = v.z; X[r][d0+3] = v.w;
    }
    __syncthreads();
    float acc[16];
    #pragma unroll
    for (int r = 0; r < 16; ++r) acc[r] = 0.f;
    const float4* wp = (const float4*)(vpw + t * D_);
    for (int c = 0; c < 64; ++c) {
        float4 w = wp[c];
        const int d0 = c << 2;
        #pragma unroll
        for (int r = 0; r < 16; ++r) {
            const float* xp = &X[r][d0];
            acc[r] += DOT4(xp, w);
        }
    }
    const float bias = vpb[t];
    const int b = (int)(gr0 / LV_);
    const int l0 = (int)(gr0 % LV_);
    const int h = t >> 5, hd = t & 31;
    const size_t base = ((size_t)(b * NH_ + h) * LV_ + l0) * HD_ + hd;
    #pragma unroll
    for (int r = 0; r < 16; ++r) vout[base + (size_t)r * HD_] = acc[r] + bias;
}

// ---------------- K2: box attention + output proj + residual + LN1 -> src1 (f32) ----------------
__global__ __launch_bounds__(256) void k_attn(
        const float* __restrict__ src, const float* __restrict__ pos,
        const float* __restrict__ refw,
        const float* __restrict__ opw, const float* __restrict__ opb,
        const float* __restrict__ boxw, const float* __restrict__ boxb,
        const float* __restrict__ attw, const float* __restrict__ attb,
        const float* __restrict__ ln1w, const float* __restrict__ ln1b,
        const float* __restrict__ vws, float* __restrict__ src1) {
    __shared__ float XQ[8][D_];     // query rows (src+pos)
    __shared__ float SS[8][D_];     // src rows (residual)
    __shared__ float AWL[8][128];   // attention logits -> softmax'd weights
    __shared__ float OBL[8][128];   // box offsets
    __shared__ float SMP[8][D_];    // sampled attention output
    __shared__ float CW[128][4];    // per-(h,nl,p) corner weights (x attn weight)
    __shared__ int   CIDX[128][4];  // per-(h,nl,p) corner flat spatial idx (level offset folded)
    __shared__ float RW[8][8];      // ref_windows rows
    __shared__ float red1[4], red2[4];
    const int t = threadIdx.x;
    const long gr0 = (long)blockIdx.x * 8;
    const int b = (int)(gr0 / LV_);
    // ---- stage q and src rows ----
    {
        const float4* sp = (const float4*)(src + gr0 * D_);
        const float4* pp = (const float4*)(pos + gr0 * D_);
        #pragma unroll
        for (int i = 0; i < 2; ++i) {
            int ii = t + i * 256;             // 512 float4 = 8 rows x 256
            float4 a = sp[ii], c = pp[ii];
            int r = ii >> 6, d0 = (ii & 63) << 2;
            SS[r][d0]   = a.x; SS[r][d0+1] = a.y; SS[r][d0+2] = a.z; SS[r][d0+3] = a.w;
            XQ[r][d0]   = a.x + c.x; XQ[r][d0+1] = a.y + c.y;
            XQ[r][d0+2] = a.z + c.z; XQ[r][d0+3] = a.w + c.w;
        }
        if (t < 56) {
            int r2 = t / 7, k = t % 7;
            RW[r2][k] = refw[(gr0 + r2) * 7 + k];
        }
    }
    __syncthreads();
    // ---- att (t<128) / box (t>=128) GEMM over 8 rows ----
    {
        const int row = t & 127;
        const float* Wm = (t < 128) ? attw : boxw;
        float acc[8];
        #pragma unroll
        for (int r = 0; r < 8; ++r) acc[r] = 0.f;
        const float4* wp = (const float4*)(Wm + row * D_);
        for (int c = 0; c < 64; ++c) {
            float4 w = wp[c];
            const int d0 = c << 2;
            #pragma unroll
            for (int r = 0; r < 8; ++r) {
                const float* xp = &XQ[r][d0];
                acc[r] += DOT4(xp, w);
            }
        }
        const float bias = ((t < 128) ? attb : boxb)[row];
        #pragma unroll
        for (int r = 0; r < 8; ++r) {
            float v = acc[r] + bias;
            if (t < 128) AWL[r][row] = v; else OBL[r][row] = v;
        }
    }
    __syncthreads();
    // ---- softmax over 16 per (row, head) ----
    if (t < 64) {
        const int r = t >> 3, h = t & 7;
        float* a = &AWL[r][h * 16];
        float m = a[0];
        #pragma unroll
        for (int k = 1; k < 16; ++k) m = fmaxf(m, a[k]);
        float s = 0.f;
        float e[16];
        #pragma unroll
        for (int k = 0; k < 16; ++k) { e[k] = __expf(a[k] - m); s += e[k]; }
        const float inv = 1.f / s;
        #pragma unroll
        for (int k = 0; k < 16; ++k) a[k] = e[k] * inv;
    }
    // ---- per-row: grid computation + bilinear gather ----
    for (int r = 0; r < 8; ++r) {
        __syncthreads();   // protect CW/CIDX from previous row's readers; also fences softmax (r=0)
        if (t < 128) {
            const int h = t >> 4, nl = (t >> 2) & 3, p = t & 3;
            const float rw0 = RW[r][0], rw1 = RW[r][1], rw3 = RW[r][3], rw4 = RW[r][4], ang = RW[r][6];
            const int obb = h * 16 + nl * 4;
            const float ob0 = OBL[r][obb + 0];
            const float ob1 = OBL[r][obb + 1];
            const float ob2 = OBL[r][obb + 2];
            const float ob3 = OBL[r][obb + 3];
            const float cx = rw0 + ob0 * 0.125f * rw3;
            const float cy = rw1 + ob1 * 0.125f * rw4;
            const float bw = fmaxf(rw3 + ob2 * 0.125f * rw3, 0.f);
            const float bh = fmaxf(rw4 + ob3 * 0.125f * rw4, 0.f);
            const float kx = (p & 1) ? 0.25f : -0.25f;
            const float ky = (p >> 1) ? 0.25f : -0.25f;
            float sth, cth;
            __sincosf(ang, &sth, &cth);
            const float g0 = kx * bw, g1 = ky * bh;
            const float gx = cx + g0 * cth - g1 * sth;
            const float gy = cy + g0 * sth + g1 * cth;
            const int Wl = 128 >> nl;                         // square levels: H == W
            const int st = (65536 - (65536 >> (2 * nl))) / 3; // 0,16384,20480,21504
            const float x = gx * Wl - 0.5f, y = gy * Wl - 0.5f;
            const float xf = floorf(x), yf = floorf(y);
            const float wx = x - xf, wy = y - yf;
            const int x0 = (int)xf, y0 = (int)yf;
            const float awv = AWL[r][t];
            #pragma unroll
            for (int c4 = 0; c4 < 4; ++c4) {
                const int dx = c4 & 1, dy = c4 >> 1;
                const int xi = x0 + dx, yi = y0 + dy;
                const float wgt = (dx ? wx : 1.f - wx) * (dy ? wy : 1.f - wy);
                const bool valid = (xi >= 0) && (xi < Wl) && (yi >= 0) && (yi < Wl);
                const int xc = xi < 0 ? 0 : (xi > Wl - 1 ? Wl - 1 : xi);
                const int yc = yi < 0 ? 0 : (yi > Wl - 1 ? Wl - 1 : yi);
                CW[t][c4] = valid ? wgt * awv : 0.f;
                CIDX[t][c4] = st + yc * Wl + xc;
            }
        }
        __syncthreads();
        {
            const int h = t >> 5, hd = t & 31;
            const size_t vbase = ((size_t)(b * NH_ + h) * LV_) * HD_ + hd;
            float acc = 0.f;
            #pragma unroll 4
            for (int k = 0; k < 16; ++k) {
                const int u = h * 16 + k;
                #pragma unroll
                for (int c4 = 0; c4 < 4; ++c4) {
                    const float w = CW[u][c4];
                    const int idx = CIDX[u][c4];
                    acc += w * vws[vbase + (size_t)idx * HD_];
                }
            }
            SMP[r][t] = acc;
        }
    }
    __syncthreads();
    // ---- output projection + residual + LN1 ----
    {
        float acc[8];
        #pragma unroll
        for (int r = 0; r < 8; ++r) acc[r] = 0.f;
        const float4* wp = (const float4*)(opw + t * D_);
        for (int c = 0; c < 64; ++c) {
            float4 w = wp[c];
            const int d0 = c << 2;
            #pragma unroll
            for (int r = 0; r < 8; ++r) {
                const float* xp = &SMP[r][d0];
                acc[r] += DOT4(xp, w);
            }
        }
        const float bias = opb[t];
        const float w1 = ln1w[t], b1 = ln1b[t];
        float yv[8];
        #pragma unroll
        for (int r = 0; r < 8; ++r) yv[r] = SS[r][t] + acc[r] + bias;
        for (int r = 0; r < 8; ++r) {
            const float v = yv[r];
            float s1 = v, s2 = v * v;
            #pragma unroll
            for (int off = 32; off; off >>= 1) {
                s1 += __shfl_down(s1, off);
                s2 += __shfl_down(s2, off);
            }
            if ((t & 63) == 0) { red1[t >> 6] = s1; red2[t >> 6] = s2; }
            __syncthreads();
            const float a1 = red1[0] + red1[1] + red1[2] + red1[3];
            const float a2 = red2[0] + red2[1] + red2[2] + red2[3];
            const float m  = a1 * (1.f / 256.f);
            const float var = a2 * (1.f / 256.f) - m * m;
            const float rs = rsqrtf(var + EPS_);
            src1[(size_t)(gr0 + r) * D_ + t] = (v - m) * rs * w1 + b1;
            __syncthreads();
        }
    }
}

// ---------------- K3: FFN + residual + LN2 -> f32 out ----------------
__global__ __launch_bounds__(256) void k_ffn(
        const float* __restrict__ src1,
        const float* __restrict__ l1w, const float* __restrict__ l1b,
        const float* __restrict__ l2w, const float* __restrict__ l2b,
        const float* __restrict__ ln2w, const float* __restrict__ ln2b,
        float* __restrict__ outp) {
    __shared__ float X[8][D_];
    __shared__ float Hs[8][DFF_];
    __shared__ float red1[4], red2[4];
    const int t = threadIdx.x;
    const long gr0 = (long)blockIdx.x * 8;
    const float4* sp = (const float4*)(src1 + gr0 * D_);
    #pragma unroll
    for (int i = 0; i < 2; ++i) {
        int ii = t + i * 256;
        float4 v = sp[ii];
        int r = ii >> 6, d0 = (ii & 63) << 2;
        X[r][d0] = v.x; X[r][d0+1] = v.y; X[r][d0+2] = v.z; X[r][d0+3] = v.w;
    }
    __syncthreads();
    // lin1 + relu -> Hs
    for (int jj = 0; jj < 4; ++jj) {
        const int j = (jj << 8) + t;
        float acc[8];
        #pragma unroll
        for (int r = 0; r < 8; ++r) acc[r] = 0.f;
        const float4* wp = (const float4*)(l1w + (size_t)j * D_);
        for (int c = 0; c < 64; ++c) {
            float4 w = wp[c];
            const int d0 = c << 2;
            #pragma unroll
            for (int r = 0; r < 8; ++r) {
                const float* xp = &X[r][d0];
                acc[r] += DOT4(xp, w);
            }
        }
        const float bias = l1b[j];
        #pragma unroll
        for (int r = 0; r < 8; ++r) Hs[r][j] = fmaxf(acc[r] + bias, 0.f);
    }
    __syncthreads();
    // lin2
    float acc2[8];
    #pragma unroll
    for (int r = 0; r < 8; ++r) acc2[r] = 0.f;
    const float4* wp2 = (const float4*)(l2w + (size_t)t * DFF_);
    for (int c = 0; c < 256; ++c) {
        float4 w = wp2[c];
        const int j0 = c << 2;
        #pragma unroll
        for (int r = 0; r < 8; ++r) {
            const float* hp = &Hs[r][j0];
            acc2[r] += DOT4(hp, w);
        }
    }
    const float bias2 = l2b[t];
    const float w2 = ln2w[t], b2 = ln2b[t];
    for (int r = 0; r < 8; ++r) {
        const float v = X[r][t] + acc2[r] + bias2;
        float s1 = v, s2 = v * v;
        #pragma unroll
        for (int off = 32; off; off >>= 1) {
            s1 += __shfl_down(s1, off);
            s2 += __shfl_down(s2, off);
        }
        if ((t & 63) == 0) { red1[t >> 6] = s1; red2[t >> 6] = s2; }
        __syncthreads();
        const float a1 = red1[0] + red1[1] + red1[2] + red1[3];
        const float a2 = red2[0] + red2[1] + red2[2] + red2[3];
        const float m  = a1 * (1.f / 256.f);
        const float var = a2 * (1.f / 256.f) - m * m;
        const float rs = rsqrtf(var + EPS_);
        outp[(size_t)(gr0 + r) * D_ + t] = (v - m) * rs * w2 + b2;
        __syncthreads();
    }
}

extern "C" void kernel_launch(void* const* d_in, const int* in_sizes, int n_in,
                              void* d_out, int out_size, void* d_ws, size_t ws_size,
                              hipStream_t stream) {
    const float* src  = (const float*)d_in[0];
    const float* pos  = (const float*)d_in[1];
    const float* refw = (const float*)d_in[4];
    const float* vpw  = (const float*)d_in[5];
    const float* vpb  = (const float*)d_in[6];
    const float* opw  = (const float*)d_in[7];
    const float* opb  = (const float*)d_in[8];
    const float* boxw = (const float*)d_in[9];
    const float* boxb = (const float*)d_in[10];
    const float* attw = (const float*)d_in[11];
    const float* attb = (const float*)d_in[12];
    const float* l1w  = (const float*)d_in[13];
    const float* l1b  = (const float*)d_in[14];
    const float* l2w  = (const float*)d_in[15];
    const float* l2b  = (const float*)d_in[16];
    const float* ln1w = (const float*)d_in[17];
    const float* ln1b = (const float*)d_in[18];
    const float* ln2w = (const float*)d_in[19];
    const float* ln2b = (const float*)d_in[20];

    float* vws  = (float*)d_ws;                                        // 2*8*21760*32 f32 = 44.6 MB
    float* src1 = (float*)((char*)d_ws + (size_t)2*NH_*LV_*HD_*4);     // 44.6 MB f32
    float* outp = (float*)d_out;

    hipLaunchKernelGGL(k_vproj, dim3(2720), dim3(256), 0, stream, src, vpw, vpb, vws);
    hipLaunchKernelGGL(k_attn,  dim3(5440), dim3(256), 0, stream,
                       src, pos, refw, opw, opb, boxw, boxb, attw, attb, ln1w, ln1b, vws, src1);
    hipLaunchKernelGGL(k_ffn,   dim3(5440), dim3(256), 0, stream,
                       src1, l1w, l1b, l2w, l2b, ln2w, ln2b, outp);
}

// Round 3
// 781.983 us; speedup vs baseline: 2.6788x; 2.6788x over previous
//
#include <hip/hip_runtime.h>
#include <stdint.h>

typedef unsigned short u16;
typedef __attribute__((ext_vector_type(8))) short short8;
typedef __attribute__((ext_vector_type(4))) float f32x4;

#define D_    256
#define NH_   8
#define HD_   32
#define LV_   21760
#define DFF_  1024
#define EPS_  1e-5f
#define MH_   21760   // rows per half (total M = 43520)

__device__ __forceinline__ float bf2f(u16 u) {
    union { uint32_t i; float f; } x; x.i = ((uint32_t)u) << 16; return x.f;
}
__device__ __forceinline__ u16 f2bf(float f) {
    union { float f; uint32_t i; } x; x.f = f;
    uint32_t r = x.i + 0x7FFFu + ((x.i >> 16) & 1u);
    return (u16)(r >> 16);
}

#define DOT4(XP, W) ((XP)[0]*(W).x + (XP)[1]*(W).y + (XP)[2]*(W).z + (XP)[3]*(W).w)

// ---------------- K0: f32 -> bf16 weight conversion ----------------
__global__ __launch_bounds__(256) void k_cvt(const float* __restrict__ in,
                                             u16* __restrict__ out, int n4) {
    int i = blockIdx.x * 256 + threadIdx.x;
    if (i < n4) {
        float4 v = ((const float4*)in)[i];
        u16 o[4] = { f2bf(v.x), f2bf(v.y), f2bf(v.z), f2bf(v.w) };
        *(uint2*)(out + (size_t)i * 4) = *(const uint2*)o;
    }
}

// ---------------- K1: value projection -> bf16 v[b,h,l,hd] ----------------
__global__ __launch_bounds__(256) void k_vproj(
        const float* __restrict__ src, const float* __restrict__ vpw,
        const float* __restrict__ vpb, u16* __restrict__ vout) {
    __shared__ float X[16][D_];
    const int t = threadIdx.x;
    const long gr0 = (long)blockIdx.x * 16;
    const float4* sp = (const float4*)(src + gr0 * D_);
    #pragma unroll
    for (int i = 0; i < 4; ++i) {
        int ii = t + i * 256;
        float4 v = sp[ii];
        int r = ii >> 6, d0 = (ii & 63) << 2;
        X[r][d0] = v.x; X[r][d0+1] = v.y; X[r][d0+2] = v.z; X[r][d0+3] = v.w;
    }
    __syncthreads();
    float acc[16];
    #pragma unroll
    for (int r = 0; r < 16; ++r) acc[r] = 0.f;
    const float4* wp = (const float4*)(vpw + t * D_);
    for (int c = 0; c < 64; ++c) {
        float4 w = wp[c];
        const int d0 = c << 2;
        #pragma unroll
        for (int r = 0; r < 16; ++r) {
            const float* xp = &X[r][d0];
            acc[r] += DOT4(xp, w);
        }
    }
    const float bias = vpb[t];
    const int b = (int)(gr0 / LV_);
    const int l0 = (int)(gr0 % LV_);
    const int h = t >> 5, hd = t & 31;
    const size_t base = ((size_t)(b * NH_ + h) * LV_ + l0) * HD_ + hd;
    #pragma unroll
    for (int r = 0; r < 16; ++r) vout[base + (size_t)r * HD_] = f2bf(acc[r] + bias);
}

// ---------------- K2: box attention + out-proj + residual + LN1 -> bf16 src1 ----------------
__global__ __launch_bounds__(256) void k_attn(
        const float* __restrict__ src, const float* __restrict__ pos,
        const float* __restrict__ refw,
        const float* __restrict__ opw, const float* __restrict__ opb,
        const float* __restrict__ boxw, const float* __restrict__ boxb,
        const float* __restrict__ attw, const float* __restrict__ attb,
        const float* __restrict__ ln1w, const float* __restrict__ ln1b,
        const u16* __restrict__ vws, u16* __restrict__ src1b) {
    __shared__ float XQ[8][D_];
    __shared__ float SS[8][D_];
    __shared__ float AWL[8][128];
    __shared__ float OBL[8][128];
    __shared__ float SMP[8][D_];
    __shared__ float CW[128][4];
    __shared__ int   CIDX[128][4];
    __shared__ float RW[8][8];
    __shared__ float red1[4], red2[4];
    const int t = threadIdx.x;
    const long gr0 = (long)blockIdx.x * 8;
    const int b = (int)(gr0 / LV_);
    {
        const float4* sp = (const float4*)(src + gr0 * D_);
        const float4* pp = (const float4*)(pos + gr0 * D_);
        #pragma unroll
        for (int i = 0; i < 2; ++i) {
            int ii = t + i * 256;
            float4 a = sp[ii], c = pp[ii];
            int r = ii >> 6, d0 = (ii & 63) << 2;
            SS[r][d0]   = a.x; SS[r][d0+1] = a.y; SS[r][d0+2] = a.z; SS[r][d0+3] = a.w;
            XQ[r][d0]   = a.x + c.x; XQ[r][d0+1] = a.y + c.y;
            XQ[r][d0+2] = a.z + c.z; XQ[r][d0+3] = a.w + c.w;
        }
        if (t < 56) {
            int r2 = t / 7, k = t % 7;
            RW[r2][k] = refw[(gr0 + r2) * 7 + k];
        }
    }
    __syncthreads();
    {
        const int row = t & 127;
        const float* Wm = (t < 128) ? attw : boxw;
        float acc[8];
        #pragma unroll
        for (int r = 0; r < 8; ++r) acc[r] = 0.f;
        const float4* wp = (const float4*)(Wm + row * D_);
        for (int c = 0; c < 64; ++c) {
            float4 w = wp[c];
            const int d0 = c << 2;
            #pragma unroll
            for (int r = 0; r < 8; ++r) {
                const float* xp = &XQ[r][d0];
                acc[r] += DOT4(xp, w);
            }
        }
        const float bias = ((t < 128) ? attb : boxb)[row];
        #pragma unroll
        for (int r = 0; r < 8; ++r) {
            float v = acc[r] + bias;
            if (t < 128) AWL[r][row] = v; else OBL[r][row] = v;
        }
    }
    __syncthreads();
    if (t < 64) {
        const int r = t >> 3, h = t & 7;
        float* a = &AWL[r][h * 16];
        float m = a[0];
        #pragma unroll
        for (int k = 1; k < 16; ++k) m = fmaxf(m, a[k]);
        float s = 0.f;
        float e[16];
        #pragma unroll
        for (int k = 0; k < 16; ++k) { e[k] = __expf(a[k] - m); s += e[k]; }
        const float inv = 1.f / s;
        #pragma unroll
        for (int k = 0; k < 16; ++k) a[k] = e[k] * inv;
    }
    for (int r = 0; r < 8; ++r) {
        __syncthreads();
        if (t < 128) {
            const int h = t >> 4, nl = (t >> 2) & 3, p = t & 3;
            const float rw0 = RW[r][0], rw1 = RW[r][1], rw3 = RW[r][3], rw4 = RW[r][4], ang = RW[r][6];
            const int obb = h * 16 + nl * 4;
            const float ob0 = OBL[r][obb + 0];
            const float ob1 = OBL[r][obb + 1];
            const float ob2 = OBL[r][obb + 2];
            const float ob3 = OBL[r][obb + 3];
            const float cx = rw0 + ob0 * 0.125f * rw3;
            const float cy = rw1 + ob1 * 0.125f * rw4;
            const float bw = fmaxf(rw3 + ob2 * 0.125f * rw3, 0.f);
            const float bh = fmaxf(rw4 + ob3 * 0.125f * rw4, 0.f);
            const float kx = (p & 1) ? 0.25f : -0.25f;
            const float ky = (p >> 1) ? 0.25f : -0.25f;
            float sth, cth;
            __sincosf(ang, &sth, &cth);
            const float g0 = kx * bw, g1 = ky * bh;
            const float gx = cx + g0 * cth - g1 * sth;
            const float gy = cy + g0 * sth + g1 * cth;
            const int Wl = 128 >> nl;
            const int st = (65536 - (65536 >> (2 * nl))) / 3;
            const float x = gx * Wl - 0.5f, y = gy * Wl - 0.5f;
            const float xf = floorf(x), yf = floorf(y);
            const float wx = x - xf, wy = y - yf;
            const int x0 = (int)xf, y0 = (int)yf;
            const float awv = AWL[r][t];
            #pragma unroll
            for (int c4 = 0; c4 < 4; ++c4) {
                const int dx = c4 & 1, dy = c4 >> 1;
                const int xi = x0 + dx, yi = y0 + dy;
                const float wgt = (dx ? wx : 1.f - wx) * (dy ? wy : 1.f - wy);
                const bool valid = (xi >= 0) && (xi < Wl) && (yi >= 0) && (yi < Wl);
                const int xc = xi < 0 ? 0 : (xi > Wl - 1 ? Wl - 1 : xi);
                const int yc = yi < 0 ? 0 : (yi > Wl - 1 ? Wl - 1 : yi);
                CW[t][c4] = valid ? wgt * awv : 0.f;
                CIDX[t][c4] = st + yc * Wl + xc;
            }
        }
        __syncthreads();
        {
            const int h = t >> 5, hd = t & 31;
            const size_t vbase = ((size_t)(b * NH_ + h) * LV_) * HD_ + hd;
            float acc = 0.f;
            #pragma unroll 4
            for (int k = 0; k < 16; ++k) {
                const int u = h * 16 + k;
                #pragma unroll
                for (int c4 = 0; c4 < 4; ++c4) {
                    const float w = CW[u][c4];
                    const int idx = CIDX[u][c4];
                    acc += w * bf2f(vws[vbase + (size_t)idx * HD_]);
                }
            }
            SMP[r][t] = acc;
        }
    }
    __syncthreads();
    {
        float acc[8];
        #pragma unroll
        for (int r = 0; r < 8; ++r) acc[r] = 0.f;
        const float4* wp = (const float4*)(opw + t * D_);
        for (int c = 0; c < 64; ++c) {
            float4 w = wp[c];
            const int d0 = c << 2;
            #pragma unroll
            for (int r = 0; r < 8; ++r) {
                const float* xp = &SMP[r][d0];
                acc[r] += DOT4(xp, w);
            }
        }
        const float bias = opb[t];
        const float w1 = ln1w[t], b1 = ln1b[t];
        float yv[8];
        #pragma unroll
        for (int r = 0; r < 8; ++r) yv[r] = SS[r][t] + acc[r] + bias;
        for (int r = 0; r < 8; ++r) {
            const float v = yv[r];
            float s1 = v, s2 = v * v;
            #pragma unroll
            for (int off = 32; off; off >>= 1) {
                s1 += __shfl_down(s1, off);
                s2 += __shfl_down(s2, off);
            }
            if ((t & 63) == 0) { red1[t >> 6] = s1; red2[t >> 6] = s2; }
            __syncthreads();
            const float a1 = red1[0] + red1[1] + red1[2] + red1[3];
            const float a2 = red2[0] + red2[1] + red2[2] + red2[3];
            const float m  = a1 * (1.f / 256.f);
            const float var = a2 * (1.f / 256.f) - m * m;
            const float rs = rsqrtf(var + EPS_);
            src1b[(size_t)(gr0 + r) * D_ + t] = f2bf((v - m) * rs * w1 + b1);
            __syncthreads();
        }
    }
}

// ---------------- K3: MFMA GEMM1: H = relu(src1 @ l1w^T + b), bf16 out ----------------
// BM=64 BN=64 BK=32, 4 waves (2x2), each 32x32 via 16x16x32 bf16 MFMA.
__global__ __launch_bounds__(256) void k_gemm1(
        const u16* __restrict__ A,      // [MH_][256] bf16
        const u16* __restrict__ Bw,     // [1024][256] bf16
        const float* __restrict__ bias, // [1024]
        u16* __restrict__ H) {          // [MH_][1024] bf16
    __shared__ u16 As[2][64 * 32];
    __shared__ u16 Bs[2][64 * 32];
    const int t = threadIdx.x;
    const int l = t & 63, w = t >> 6;
    const int m0 = blockIdx.x * 64, n0 = blockIdx.y * 64;
    // staging: thread t handles tile row sr = t>>2, 16B chunk sc = t&3 (linear global read,
    // XOR-swizzled LDS slot so frag ds_read_b128 is conflict-free)
    const int sr = t >> 2, sc = t & 3;
    const int wslot = sr * 32 + ((sc ^ ((sr >> 1) & 3)) << 3);
    const u16* gA = A + (size_t)(m0 + sr) * 256 + sc * 8;
    const u16* gB = Bw + (size_t)(n0 + sr) * 256 + sc * 8;
    const int fr = l & 15, fg = l >> 4;
    const int wm = w >> 1, wn = w & 1;

    f32x4 acc[2][2];
    #pragma unroll
    for (int mi = 0; mi < 2; ++mi)
        #pragma unroll
        for (int ni = 0; ni < 2; ++ni)
            acc[mi][ni] = (f32x4){0.f, 0.f, 0.f, 0.f};

    // prologue: tile 0
    *(uint4*)&As[0][wslot] = *(const uint4*)(gA);
    *(uint4*)&Bs[0][wslot] = *(const uint4*)(gB);
    __syncthreads();

    for (int kt = 0; kt < 8; ++kt) {
        const int cur = kt & 1;
        uint4 na, nb;
        if (kt < 7) {
            na = *(const uint4*)(gA + (kt + 1) * 32);
            nb = *(const uint4*)(gB + (kt + 1) * 32);
        }
        short8 af[2], bfr[2];
        #pragma unroll
        for (int mi = 0; mi < 2; ++mi) {
            const int r = wm * 32 + mi * 16 + fr;
            af[mi] = *(const short8*)&As[cur][r * 32 + ((fg ^ ((r >> 1) & 3)) << 3)];
        }
        #pragma unroll
        for (int ni = 0; ni < 2; ++ni) {
            const int r = wn * 32 + ni * 16 + fr;
            bfr[ni] = *(const short8*)&Bs[cur][r * 32 + ((fg ^ ((r >> 1) & 3)) << 3)];
        }
        #pragma unroll
        for (int mi = 0; mi < 2; ++mi)
            #pragma unroll
            for (int ni = 0; ni < 2; ++ni)
                acc[mi][ni] = __builtin_amdgcn_mfma_f32_16x16x32_bf16(af[mi], bfr[ni], acc[mi][ni], 0, 0, 0);
        if (kt < 7) {
            *(uint4*)&As[cur ^ 1][wslot] = na;
            *(uint4*)&Bs[cur ^ 1][wslot] = nb;
            __syncthreads();
        }
    }
    // epilogue: bias + relu -> bf16
    #pragma unroll
    for (int ni = 0; ni < 2; ++ni) {
        const int n = n0 + wn * 32 + ni * 16 + fr;
        const float bv = bias[n];
        #pragma unroll
        for (int mi = 0; mi < 2; ++mi) {
            #pragma unroll
            for (int q = 0; q < 4; ++q) {
                const int m = m0 + wm * 32 + mi * 16 + fg * 4 + q;
                const float v = acc[mi][ni][q] + bv;
                H[(size_t)m * 1024 + n] = f2bf(fmaxf(v, 0.f));
            }
        }
    }
}

// ---------------- K4: MFMA GEMM2 + bias + residual + LN2 -> f32 out ----------------
// BM=32 BN=256 BK=32, 4 waves (1x4), each 32x64. Whole output row in-block for LN.
__global__ __launch_bounds__(256) void k_gemm2(
        const u16* __restrict__ A,      // H [MH_][1024] bf16
        const u16* __restrict__ Bw,     // l2w [256][1024] bf16
        const float* __restrict__ bias, // l2b [256]
        const u16* __restrict__ resid,  // src1 bf16 [MH_][256]
        const float* __restrict__ lnw, const float* __restrict__ lnb,
        float* __restrict__ out) {      // [MH_][256]
    __shared__ char smem[36864];        // staging (36 KB); Y (32 KB) overlays after k-loop
    u16* As = (u16*)smem;               // [2][32*32]
    u16* Bs = (u16*)(smem + 4096);      // [2][256*32]
    float* Y = (float*)smem;            // [32][256]
    const int t = threadIdx.x;
    const int l = t & 63, w = t >> 6;
    const int m0 = blockIdx.x * 32;
    // A staging: threads 0..127, row t>>2, chunk t&3
    const int sAr = t >> 2, sc = t & 3;
    const int aslot = sAr * 32 + ((sc ^ ((sAr >> 1) & 3)) << 3);
    const u16* gA = A + (size_t)(m0 + sAr) * 1024 + sc * 8;
    // B staging: 4 rows per thread
    const u16* gB[4];
    int bslot[4];
    #pragma unroll
    for (int i = 0; i < 4; ++i) {
        const int r = (t >> 2) + i * 64;
        gB[i] = Bw + (size_t)r * 1024 + sc * 8;
        bslot[i] = r * 32 + ((sc ^ ((r >> 1) & 3)) << 3);
    }
    const int fr = l & 15, fg = l >> 4;

    f32x4 acc[2][4];
    #pragma unroll
    for (int mi = 0; mi < 2; ++mi)
        #pragma unroll
        for (int ni = 0; ni < 4; ++ni)
            acc[mi][ni] = (f32x4){0.f, 0.f, 0.f, 0.f};

    if (t < 128) *(uint4*)&As[aslot] = *(const uint4*)(gA);
    #pragma unroll
    for (int i = 0; i < 4; ++i) *(uint4*)&Bs[bslot[i]] = *(const uint4*)(gB[i]);
    __syncthreads();

    for (int kt = 0; kt < 32; ++kt) {
        const int cur = kt & 1;
        uint4 na, nb[4];
        if (kt < 31) {
            if (t < 128) na = *(const uint4*)(gA + (kt + 1) * 32);
            #pragma unroll
            for (int i = 0; i < 4; ++i) nb[i] = *(const uint4*)(gB[i] + (kt + 1) * 32);
        }
        short8 af[2], bfr[4];
        #pragma unroll
        for (int mi = 0; mi < 2; ++mi) {
            const int r = mi * 16 + fr;
            af[mi] = *(const short8*)&As[cur * 1024 + r * 32 + ((fg ^ ((r >> 1) & 3)) << 3)];
        }
        #pragma unroll
        for (int ni = 0; ni < 4; ++ni) {
            const int r = w * 64 + ni * 16 + fr;
            bfr[ni] = *(const short8*)&Bs[cur * 8192 + r * 32 + ((fg ^ ((r >> 1) & 3)) << 3)];
        }
        #pragma unroll
        for (int mi = 0; mi < 2; ++mi)
            #pragma unroll
            for (int ni = 0; ni < 4; ++ni)
                acc[mi][ni] = __builtin_amdgcn_mfma_f32_16x16x32_bf16(af[mi], bfr[ni], acc[mi][ni], 0, 0, 0);
        if (kt < 31) {
            if (t < 128) *(uint4*)&As[(cur ^ 1) * 1024 + aslot] = na;
            #pragma unroll
            for (int i = 0; i < 4; ++i) *(uint4*)&Bs[(cur ^ 1) * 8192 + bslot[i]] = nb[i];
            __syncthreads();
        }
    }
    __syncthreads();   // staging reads done -> safe to overlay Y
    // y = acc + bias + residual
    #pragma unroll
    for (int ni = 0; ni < 4; ++ni) {
        const int n = w * 64 + ni * 16 + fr;
        const float bv = bias[n];
        #pragma unroll
        for (int mi = 0; mi < 2; ++mi) {
            #pragma unroll
            for (int q = 0; q < 4; ++q) {
                const int ml = mi * 16 + fg * 4 + q;
                Y[ml * 256 + n] = acc[mi][ni][q] + bv + bf2f(resid[(size_t)(m0 + ml) * 256 + n]);
            }
        }
    }
    __syncthreads();
    // LN: wave w handles rows w*8 .. w*8+7
    for (int rr = 0; rr < 8; ++rr) {
        const int m = w * 8 + rr;
        const float v0 = Y[m * 256 + l];
        const float v1 = Y[m * 256 + 64 + l];
        const float v2 = Y[m * 256 + 128 + l];
        const float v3 = Y[m * 256 + 192 + l];
        float s1 = v0 + v1 + v2 + v3;
        float s2 = v0 * v0 + v1 * v1 + v2 * v2 + v3 * v3;
        #pragma unroll
        for (int off = 32; off; off >>= 1) {
            s1 += __shfl_xor(s1, off);
            s2 += __shfl_xor(s2, off);
        }
        const float mean = s1 * (1.f / 256.f);
        const float var = s2 * (1.f / 256.f) - mean * mean;
        const float rs = rsqrtf(var + EPS_);
        const size_t ob = (size_t)(m0 + m) * 256;
        out[ob + l]        = (v0 - mean) * rs * lnw[l]        + lnb[l];
        out[ob + 64 + l]   = (v1 - mean) * rs * lnw[64 + l]   + lnb[64 + l];
        out[ob + 128 + l]  = (v2 - mean) * rs * lnw[128 + l]  + lnb[128 + l];
        out[ob + 192 + l]  = (v3 - mean) * rs * lnw[192 + l]  + lnb[192 + l];
    }
}

extern "C" void kernel_launch(void* const* d_in, const int* in_sizes, int n_in,
                              void* d_out, int out_size, void* d_ws, size_t ws_size,
                              hipStream_t stream) {
    const float* src  = (const float*)d_in[0];
    const float* pos  = (const float*)d_in[1];
    const float* refw = (const float*)d_in[4];
    const float* vpw  = (const float*)d_in[5];
    const float* vpb  = (const float*)d_in[6];
    const float* opw  = (const float*)d_in[7];
    const float* opb  = (const float*)d_in[8];
    const float* boxw = (const float*)d_in[9];
    const float* boxb = (const float*)d_in[10];
    const float* attw = (const float*)d_in[11];
    const float* attb = (const float*)d_in[12];
    const float* l1w  = (const float*)d_in[13];
    const float* l1b  = (const float*)d_in[14];
    const float* l2w  = (const float*)d_in[15];
    const float* l2b  = (const float*)d_in[16];
    const float* ln1w = (const float*)d_in[17];
    const float* ln1b = (const float*)d_in[18];
    const float* ln2w = (const float*)d_in[19];
    const float* ln2b = (const float*)d_in[20];

    // ws layout (total 67.9 MB):
    // [0, 44564480)           : Hbf (per-half FFN hidden, bf16) ; vws (22.3 MB) overlays here during attn
    // [44564480, 66846720)    : src1_bf (LN1 output, bf16, full M)
    // [66846720, 67371008)    : l1w bf16
    // [67371008, 67895296)    : l2w bf16
    u16* Hbf   = (u16*)d_ws;
    u16* vws   = (u16*)d_ws;
    u16* src1b = (u16*)((char*)d_ws + 44564480u);
    u16* l1wb  = (u16*)((char*)d_ws + 66846720u);
    u16* l2wb  = (u16*)((char*)d_ws + 67371008u);

    hipLaunchKernelGGL(k_cvt, dim3(256), dim3(256), 0, stream, l1w, l1wb, 65536);
    hipLaunchKernelGGL(k_cvt, dim3(256), dim3(256), 0, stream, l2w, l2wb, 65536);
    hipLaunchKernelGGL(k_vproj, dim3(2720), dim3(256), 0, stream, src, vpw, vpb, vws);
    hipLaunchKernelGGL(k_attn,  dim3(5440), dim3(256), 0, stream,
                       src, pos, refw, opw, opb, boxw, boxb, attw, attb, ln1w, ln1b, vws, src1b);
    for (int h = 0; h < 2; ++h) {
        const u16* Ah  = src1b + (size_t)h * MH_ * 256;
        float* outh    = (float*)d_out + (size_t)h * MH_ * 256;
        hipLaunchKernelGGL(k_gemm1, dim3(340, 16), dim3(256), 0, stream, Ah, l1wb, l1b, Hbf);
        hipLaunchKernelGGL(k_gemm2, dim3(680), dim3(256), 0, stream, Hbf, l2wb, l2b, Ah, ln2w, ln2b, outh);
    }
}

// Round 4
// 364.859 us; speedup vs baseline: 5.7413x; 2.1432x over previous
//
#include <hip/hip_runtime.h>
#include <stdint.h>

typedef unsigned short u16;
typedef __attribute__((ext_vector_type(8))) short short8;
typedef __attribute__((ext_vector_type(4))) float f32x4;

#define D_    256
#define NH_   8
#define HD_   32
#define LV_   21760
#define DFF_  1024
#define EPS_  1e-5f
#define MH_   21760   // rows per half (total M = 43520)
#define MT_   43520

__device__ __forceinline__ float bf2f(u16 u) {
    union { uint32_t i; float f; } x; x.i = ((uint32_t)u) << 16; return x.f;
}
__device__ __forceinline__ u16 f2bf(float f) {
    union { float f; uint32_t i; } x; x.f = f;
    uint32_t r = x.i + 0x7FFFu + ((x.i >> 16) & 1u);
    return (u16)(r >> 16);
}
__device__ __forceinline__ uint32_t pk2(float a, float b) {
    return (uint32_t)f2bf(a) | ((uint32_t)f2bf(b) << 16);
}
__device__ __forceinline__ void cv8(u16* dst, float4 a, float4 b) {
    uint4 r;
    r.x = pk2(a.x, a.y); r.y = pk2(a.z, a.w);
    r.z = pk2(b.x, b.y); r.w = pk2(b.z, b.w);
    *(uint4*)dst = r;
}
__device__ __forceinline__ void cv8add(u16* dst, float4 a, float4 a2, float4 b, float4 b2) {
    uint4 r;
    r.x = pk2(a.x + a2.x, a.y + a2.y); r.y = pk2(a.z + a2.z, a.w + a2.w);
    r.z = pk2(b.x + b2.x, b.y + b2.y); r.w = pk2(b.z + b2.z, b.w + b2.w);
    *(uint4*)dst = r;
}

// ---------------- K0: f32 -> bf16 weight conversion ----------------
__global__ __launch_bounds__(256) void k_cvt(const float* __restrict__ in,
                                             u16* __restrict__ out, int n4) {
    int i = blockIdx.x * 256 + threadIdx.x;
    if (i < n4) {
        float4 v = ((const float4*)in)[i];
        uint2 r; r.x = pk2(v.x, v.y); r.y = pk2(v.z, v.w);
        *(uint2*)(out + (size_t)i * 4) = r;
    }
}

// ---------------- K1: MFMA value projection -> bf16 v[b,h,l,hd] ----------------
// BM=64 BN=64 BK=32, A = src f32 (cvt at stage), B = vpw f32 (cvt at stage)
__global__ __launch_bounds__(256) void k_vprojm(
        const float* __restrict__ src, const float* __restrict__ vpw,
        const float* __restrict__ vpb, u16* __restrict__ vout) {
    __shared__ u16 As[2][64 * 32];
    __shared__ u16 Bs[2][64 * 32];
    const int t = threadIdx.x;
    const int l = t & 63, w = t >> 6;
    const int m0 = blockIdx.x * 64, n0 = blockIdx.y * 64;
    const int sr = t >> 2, sc = t & 3;
    const int wslot = sr * 32 + ((sc ^ ((sr >> 1) & 3)) << 3);
    const float* gA = src + (size_t)(m0 + sr) * 256 + sc * 8;
    const float* gB = vpw + (size_t)(n0 + sr) * 256 + sc * 8;
    const int fr = l & 15, fg = l >> 4;
    const int wm = w >> 1, wn = w & 1;

    f32x4 acc[2][2];
    #pragma unroll
    for (int mi = 0; mi < 2; ++mi)
        #pragma unroll
        for (int ni = 0; ni < 2; ++ni)
            acc[mi][ni] = (f32x4){0.f, 0.f, 0.f, 0.f};

    cv8(&As[0][wslot], *(const float4*)gA, *(const float4*)(gA + 4));
    cv8(&Bs[0][wslot], *(const float4*)gB, *(const float4*)(gB + 4));
    __syncthreads();

    for (int kt = 0; kt < 8; ++kt) {
        const int cur = kt & 1;
        float4 na0, na1, nb0, nb1;
        if (kt < 7) {
            na0 = *(const float4*)(gA + (kt + 1) * 32);
            na1 = *(const float4*)(gA + (kt + 1) * 32 + 4);
            nb0 = *(const float4*)(gB + (kt + 1) * 32);
            nb1 = *(const float4*)(gB + (kt + 1) * 32 + 4);
        }
        short8 af[2], bfr[2];
        #pragma unroll
        for (int mi = 0; mi < 2; ++mi) {
            const int r = wm * 32 + mi * 16 + fr;
            af[mi] = *(const short8*)&As[cur][r * 32 + ((fg ^ ((r >> 1) & 3)) << 3)];
        }
        #pragma unroll
        for (int ni = 0; ni < 2; ++ni) {
            const int r = wn * 32 + ni * 16 + fr;
            bfr[ni] = *(const short8*)&Bs[cur][r * 32 + ((fg ^ ((r >> 1) & 3)) << 3)];
        }
        #pragma unroll
        for (int mi = 0; mi < 2; ++mi)
            #pragma unroll
            for (int ni = 0; ni < 2; ++ni)
                acc[mi][ni] = __builtin_amdgcn_mfma_f32_16x16x32_bf16(af[mi], bfr[ni], acc[mi][ni], 0, 0, 0);
        if (kt < 7) {
            cv8(&As[cur ^ 1][wslot], na0, na1);
            cv8(&Bs[cur ^ 1][wslot], nb0, nb1);
            __syncthreads();
        }
    }
    // epilogue: scatter to v[b,h,l,hd]
    const int b = m0 / LV_;          // 21760 % 64 == 0, no straddle
    #pragma unroll
    for (int ni = 0; ni < 2; ++ni) {
        const int n = n0 + wn * 32 + ni * 16 + fr;
        const float bv = vpb[n];
        const int h = n >> 5, hd = n & 31;
        #pragma unroll
        for (int mi = 0; mi < 2; ++mi) {
            #pragma unroll
            for (int q = 0; q < 4; ++q) {
                const int m = m0 + wm * 32 + mi * 16 + fg * 4 + q;
                const int lrow = m - b * LV_;
                vout[((size_t)(b * NH_ + h) * LV_ + lrow) * HD_ + hd] = f2bf(acc[mi][ni][q] + bv);
            }
        }
    }
}

// ---------------- K2: MFMA logits: logits[m][n] = (src+pos)[m] . W[n] + bias ----------------
// n<128: attw/attb; n>=128: boxw/boxb. BM=64 BN=64 BK=32.
__global__ __launch_bounds__(256) void k_logits(
        const float* __restrict__ src, const float* __restrict__ pos,
        const float* __restrict__ attw, const float* __restrict__ attb,
        const float* __restrict__ boxw, const float* __restrict__ boxb,
        float* __restrict__ logits) {
    __shared__ u16 As[2][64 * 32];
    __shared__ u16 Bs[2][64 * 32];
    const int t = threadIdx.x;
    const int l = t & 63, w = t >> 6;
    const int m0 = blockIdx.x * 64;
    const int n0g = blockIdx.y * 64;
    const float* Bsrc = (n0g < 128) ? (attw + (size_t)n0g * 256) : (boxw + (size_t)(n0g - 128) * 256);
    const float* bsrc = (n0g < 128) ? (attb + n0g) : (boxb + (n0g - 128));
    const int sr = t >> 2, sc = t & 3;
    const int wslot = sr * 32 + ((sc ^ ((sr >> 1) & 3)) << 3);
    const float* gAs = src + (size_t)(m0 + sr) * 256 + sc * 8;
    const float* gAp = pos + (size_t)(m0 + sr) * 256 + sc * 8;
    const float* gB  = Bsrc + (size_t)sr * 256 + sc * 8;
    const int fr = l & 15, fg = l >> 4;
    const int wm = w >> 1, wn = w & 1;

    f32x4 acc[2][2];
    #pragma unroll
    for (int mi = 0; mi < 2; ++mi)
        #pragma unroll
        for (int ni = 0; ni < 2; ++ni)
            acc[mi][ni] = (f32x4){0.f, 0.f, 0.f, 0.f};

    cv8add(&As[0][wslot], *(const float4*)gAs, *(const float4*)gAp,
                          *(const float4*)(gAs + 4), *(const float4*)(gAp + 4));
    cv8(&Bs[0][wslot], *(const float4*)gB, *(const float4*)(gB + 4));
    __syncthreads();

    for (int kt = 0; kt < 8; ++kt) {
        const int cur = kt & 1;
        float4 ns0, ns1, np0, np1, nb0, nb1;
        if (kt < 7) {
            ns0 = *(const float4*)(gAs + (kt + 1) * 32);
            ns1 = *(const float4*)(gAs + (kt + 1) * 32 + 4);
            np0 = *(const float4*)(gAp + (kt + 1) * 32);
            np1 = *(const float4*)(gAp + (kt + 1) * 32 + 4);
            nb0 = *(const float4*)(gB + (kt + 1) * 32);
            nb1 = *(const float4*)(gB + (kt + 1) * 32 + 4);
        }
        short8 af[2], bfr[2];
        #pragma unroll
        for (int mi = 0; mi < 2; ++mi) {
            const int r = wm * 32 + mi * 16 + fr;
            af[mi] = *(const short8*)&As[cur][r * 32 + ((fg ^ ((r >> 1) & 3)) << 3)];
        }
        #pragma unroll
        for (int ni = 0; ni < 2; ++ni) {
            const int r = wn * 32 + ni * 16 + fr;
            bfr[ni] = *(const short8*)&Bs[cur][r * 32 + ((fg ^ ((r >> 1) & 3)) << 3)];
        }
        #pragma unroll
        for (int mi = 0; mi < 2; ++mi)
            #pragma unroll
            for (int ni = 0; ni < 2; ++ni)
                acc[mi][ni] = __builtin_amdgcn_mfma_f32_16x16x32_bf16(af[mi], bfr[ni], acc[mi][ni], 0, 0, 0);
        if (kt < 7) {
            cv8add(&As[cur ^ 1][wslot], ns0, np0, ns1, np1);
            cv8(&Bs[cur ^ 1][wslot], nb0, nb1);
            __syncthreads();
        }
    }
    #pragma unroll
    for (int ni = 0; ni < 2; ++ni) {
        const int nl_ = wn * 32 + ni * 16 + fr;
        const float bv = bsrc[nl_];
        #pragma unroll
        for (int mi = 0; mi < 2; ++mi) {
            #pragma unroll
            for (int q = 0; q < 4; ++q) {
                const int m = m0 + wm * 32 + mi * 16 + fg * 4 + q;
                logits[(size_t)m * 256 + n0g + nl_] = acc[mi][ni][q] + bv;
            }
        }
    }
}

// ---------------- K3: sampling: softmax + grid + bilinear gather -> SMP bf16 ----------------
__global__ __launch_bounds__(256) void k_sample(
        const float* __restrict__ logits, const float* __restrict__ refw,
        const u16* __restrict__ vws, u16* __restrict__ smp) {
    __shared__ float AWL[8][128];
    __shared__ float OBL[8][128];
    __shared__ float CW[128][4];
    __shared__ int   CIDX[128][4];
    __shared__ float RW[8][8];
    const int t = threadIdx.x;
    // bijective XCD swizzle (gridDim.x = 5440 = 8*680): adjacent rows -> same XCD for L2 locality
    const int bid = blockIdx.x;
    const int sb = (bid & 7) * (gridDim.x >> 3) + (bid >> 3);
    const long gr0 = (long)sb * 8;
    const int b = (int)(gr0 / LV_);
    {
        const float4* lp = (const float4*)(logits + gr0 * 256);
        #pragma unroll
        for (int i = 0; i < 2; ++i) {
            int ii = t + i * 256;
            float4 v = lp[ii];
            int r = ii >> 6, c4 = (ii & 63) << 2;
            float* dst = (c4 < 128) ? &AWL[r][c4] : &OBL[r][c4 - 128];
            dst[0] = v.x; dst[1] = v.y; dst[2] = v.z; dst[3] = v.w;
        }
        if (t < 56) {
            int r2 = t / 7, k = t % 7;
            RW[r2][k] = refw[(gr0 + r2) * 7 + k];
        }
    }
    __syncthreads();
    if (t < 64) {
        const int r = t >> 3, h = t & 7;
        float* a = &AWL[r][h * 16];
        float m = a[0];
        #pragma unroll
        for (int k = 1; k < 16; ++k) m = fmaxf(m, a[k]);
        float s = 0.f;
        float e[16];
        #pragma unroll
        for (int k = 0; k < 16; ++k) { e[k] = __expf(a[k] - m); s += e[k]; }
        const float inv = 1.f / s;
        #pragma unroll
        for (int k = 0; k < 16; ++k) a[k] = e[k] * inv;
    }
    for (int r = 0; r < 8; ++r) {
        __syncthreads();
        if (t < 128) {
            const int h = t >> 4, nl = (t >> 2) & 3, p = t & 3;
            const float rw0 = RW[r][0], rw1 = RW[r][1], rw3 = RW[r][3], rw4 = RW[r][4], ang = RW[r][6];
            const int obb = h * 16 + nl * 4;
            const float ob0 = OBL[r][obb + 0];
            const float ob1 = OBL[r][obb + 1];
            const float ob2 = OBL[r][obb + 2];
            const float ob3 = OBL[r][obb + 3];
            const float cx = rw0 + ob0 * 0.125f * rw3;
            const float cy = rw1 + ob1 * 0.125f * rw4;
            const float bw = fmaxf(rw3 + ob2 * 0.125f * rw3, 0.f);
            const float bh = fmaxf(rw4 + ob3 * 0.125f * rw4, 0.f);
            const float kx = (p & 1) ? 0.25f : -0.25f;
            const float ky = (p >> 1) ? 0.25f : -0.25f;
            float sth, cth;
            __sincosf(ang, &sth, &cth);
            const float g0 = kx * bw, g1 = ky * bh;
            const float gx = cx + g0 * cth - g1 * sth;
            const float gy = cy + g0 * sth + g1 * cth;
            const int Wl = 128 >> nl;
            const int st = (65536 - (65536 >> (2 * nl))) / 3;
            const float x = gx * Wl - 0.5f, y = gy * Wl - 0.5f;
            const float xf = floorf(x), yf = floorf(y);
            const float wx = x - xf, wy = y - yf;
            const int x0 = (int)xf, y0 = (int)yf;
            const float awv = AWL[r][t];
            #pragma unroll
            for (int c4 = 0; c4 < 4; ++c4) {
                const int dx = c4 & 1, dy = c4 >> 1;
                const int xi = x0 + dx, yi = y0 + dy;
                const float wgt = (dx ? wx : 1.f - wx) * (dy ? wy : 1.f - wy);
                const bool valid = (xi >= 0) && (xi < Wl) && (yi >= 0) && (yi < Wl);
                const int xc = xi < 0 ? 0 : (xi > Wl - 1 ? Wl - 1 : xi);
                const int yc = yi < 0 ? 0 : (yi > Wl - 1 ? Wl - 1 : yi);
                CW[t][c4] = valid ? wgt * awv : 0.f;
                CIDX[t][c4] = st + yc * Wl + xc;
            }
        }
        __syncthreads();
        {
            const int h = t >> 5, hd = t & 31;
            const size_t vbase = ((size_t)(b * NH_ + h) * LV_) * HD_ + hd;
            float acc = 0.f;
            #pragma unroll 4
            for (int k = 0; k < 16; ++k) {
                const int u = h * 16 + k;
                #pragma unroll
                for (int c4 = 0; c4 < 4; ++c4) {
                    const float w = CW[u][c4];
                    const int idx = CIDX[u][c4];
                    acc += w * bf2f(vws[vbase + (size_t)idx * HD_]);
                }
            }
            smp[(size_t)(gr0 + r) * 256 + t] = f2bf(acc);
        }
    }
}

// ---------------- K4: MFMA out-proj + residual(src f32) + LN1 -> src1b bf16 ----------------
// BM=32 BN=256 BK=32, K=256 (8 k-steps). B = opw f32 cvt-at-stage.
__global__ __launch_bounds__(256) void k_oproj(
        const u16* __restrict__ A,      // SMP [MT_][256] bf16
        const float* __restrict__ opw,  // [256][256] f32
        const float* __restrict__ opb,
        const float* __restrict__ src,  // residual f32
        const float* __restrict__ lnw, const float* __restrict__ lnb,
        u16* __restrict__ out) {        // src1b [MT_][256] bf16
    __shared__ char smem[36864];
    u16* As = (u16*)smem;               // [2][32*32]
    u16* Bs = (u16*)(smem + 4096);      // [2][256*32]
    float* Y = (float*)smem;            // [32][256] overlay
    const int t = threadIdx.x;
    const int l = t & 63, w = t >> 6;
    const int m0 = blockIdx.x * 32;
    const int sAr = t >> 2, sc = t & 3;
    const int aslot = sAr * 32 + ((sc ^ ((sAr >> 1) & 3)) << 3);
    const u16* gA = A + (size_t)(m0 + sAr) * 256 + sc * 8;
    const float* gB[4];
    int bslot[4];
    #pragma unroll
    for (int i = 0; i < 4; ++i) {
        const int r = (t >> 2) + i * 64;
        gB[i] = opw + (size_t)r * 256 + sc * 8;
        bslot[i] = r * 32 + ((sc ^ ((r >> 1) & 3)) << 3);
    }
    const int fr = l & 15, fg = l >> 4;

    f32x4 acc[2][4];
    #pragma unroll
    for (int mi = 0; mi < 2; ++mi)
        #pragma unroll
        for (int ni = 0; ni < 4; ++ni)
            acc[mi][ni] = (f32x4){0.f, 0.f, 0.f, 0.f};

    if (t < 128) *(uint4*)&As[aslot] = *(const uint4*)gA;
    #pragma unroll
    for (int i = 0; i < 4; ++i)
        cv8(&Bs[bslot[i]], *(const float4*)gB[i], *(const float4*)(gB[i] + 4));
    __syncthreads();

    for (int kt = 0; kt < 8; ++kt) {
        const int cur = kt & 1;
        uint4 na; float4 nb[4][2];
        if (kt < 7) {
            if (t < 128) na = *(const uint4*)(gA + (kt + 1) * 32);
            #pragma unroll
            for (int i = 0; i < 4; ++i) {
                nb[i][0] = *(const float4*)(gB[i] + (kt + 1) * 32);
                nb[i][1] = *(const float4*)(gB[i] + (kt + 1) * 32 + 4);
            }
        }
        short8 af[2], bfr[4];
        #pragma unroll
        for (int mi = 0; mi < 2; ++mi) {
            const int r = mi * 16 + fr;
            af[mi] = *(const short8*)&As[cur * 1024 + r * 32 + ((fg ^ ((r >> 1) & 3)) << 3)];
        }
        #pragma unroll
        for (int ni = 0; ni < 4; ++ni) {
            const int r = w * 64 + ni * 16 + fr;
            bfr[ni] = *(const short8*)&Bs[cur * 8192 + r * 32 + ((fg ^ ((r >> 1) & 3)) << 3)];
        }
        #pragma unroll
        for (int mi = 0; mi < 2; ++mi)
            #pragma unroll
            for (int ni = 0; ni < 4; ++ni)
                acc[mi][ni] = __builtin_amdgcn_mfma_f32_16x16x32_bf16(af[mi], bfr[ni], acc[mi][ni], 0, 0, 0);
        if (kt < 7) {
            if (t < 128) *(uint4*)&As[(cur ^ 1) * 1024 + aslot] = na;
            #pragma unroll
            for (int i = 0; i < 4; ++i)
                cv8(&Bs[(cur ^ 1) * 8192 + bslot[i]], nb[i][0], nb[i][1]);
            __syncthreads();
        }
    }
    __syncthreads();
    #pragma unroll
    for (int ni = 0; ni < 4; ++ni) {
        const int n = w * 64 + ni * 16 + fr;
        const float bv = opb[n];
        #pragma unroll
        for (int mi = 0; mi < 2; ++mi) {
            #pragma unroll
            for (int q = 0; q < 4; ++q) {
                const int ml = mi * 16 + fg * 4 + q;
                Y[ml * 256 + n] = acc[mi][ni][q] + bv + src[(size_t)(m0 + ml) * 256 + n];
            }
        }
    }
    __syncthreads();
    for (int rr = 0; rr < 8; ++rr) {
        const int m = w * 8 + rr;
        const float v0 = Y[m * 256 + l];
        const float v1 = Y[m * 256 + 64 + l];
        const float v2 = Y[m * 256 + 128 + l];
        const float v3 = Y[m * 256 + 192 + l];
        float s1 = v0 + v1 + v2 + v3;
        float s2 = v0 * v0 + v1 * v1 + v2 * v2 + v3 * v3;
        #pragma unroll
        for (int off = 32; off; off >>= 1) {
            s1 += __shfl_xor(s1, off);
            s2 += __shfl_xor(s2, off);
        }
        const float mean = s1 * (1.f / 256.f);
        const float var = s2 * (1.f / 256.f) - mean * mean;
        const float rs = rsqrtf(var + EPS_);
        const size_t ob = (size_t)(m0 + m) * 256;
        out[ob + l]       = f2bf((v0 - mean) * rs * lnw[l]       + lnb[l]);
        out[ob + 64 + l]  = f2bf((v1 - mean) * rs * lnw[64 + l]  + lnb[64 + l]);
        out[ob + 128 + l] = f2bf((v2 - mean) * rs * lnw[128 + l] + lnb[128 + l]);
        out[ob + 192 + l] = f2bf((v3 - mean) * rs * lnw[192 + l] + lnb[192 + l]);
    }
}

// ---------------- K5: MFMA GEMM1: H = relu(src1 @ l1w^T + b), bf16 out ----------------
__global__ __launch_bounds__(256) void k_gemm1(
        const u16* __restrict__ A, const u16* __restrict__ Bw,
        const float* __restrict__ bias, u16* __restrict__ H) {
    __shared__ u16 As[2][64 * 32];
    __shared__ u16 Bs[2][64 * 32];
    const int t = threadIdx.x;
    const int l = t & 63, w = t >> 6;
    const int m0 = blockIdx.x * 64, n0 = blockIdx.y * 64;
    const int sr = t >> 2, sc = t & 3;
    const int wslot = sr * 32 + ((sc ^ ((sr >> 1) & 3)) << 3);
    const u16* gA = A + (size_t)(m0 + sr) * 256 + sc * 8;
    const u16* gB = Bw + (size_t)(n0 + sr) * 256 + sc * 8;
    const int fr = l & 15, fg = l >> 4;
    const int wm = w >> 1, wn = w & 1;

    f32x4 acc[2][2];
    #pragma unroll
    for (int mi = 0; mi < 2; ++mi)
        #pragma unroll
        for (int ni = 0; ni < 2; ++ni)
            acc[mi][ni] = (f32x4){0.f, 0.f, 0.f, 0.f};

    *(uint4*)&As[0][wslot] = *(const uint4*)(gA);
    *(uint4*)&Bs[0][wslot] = *(const uint4*)(gB);
    __syncthreads();

    for (int kt = 0; kt < 8; ++kt) {
        const int cur = kt & 1;
        uint4 na, nb;
        if (kt < 7) {
            na = *(const uint4*)(gA + (kt + 1) * 32);
            nb = *(const uint4*)(gB + (kt + 1) * 32);
        }
        short8 af[2], bfr[2];
        #pragma unroll
        for (int mi = 0; mi < 2; ++mi) {
            const int r = wm * 32 + mi * 16 + fr;
            af[mi] = *(const short8*)&As[cur][r * 32 + ((fg ^ ((r >> 1) & 3)) << 3)];
        }
        #pragma unroll
        for (int ni = 0; ni < 2; ++ni) {
            const int r = wn * 32 + ni * 16 + fr;
            bfr[ni] = *(const short8*)&Bs[cur][r * 32 + ((fg ^ ((r >> 1) & 3)) << 3)];
        }
        #pragma unroll
        for (int mi = 0; mi < 2; ++mi)
            #pragma unroll
            for (int ni = 0; ni < 2; ++ni)
                acc[mi][ni] = __builtin_amdgcn_mfma_f32_16x16x32_bf16(af[mi], bfr[ni], acc[mi][ni], 0, 0, 0);
        if (kt < 7) {
            *(uint4*)&As[cur ^ 1][wslot] = na;
            *(uint4*)&Bs[cur ^ 1][wslot] = nb;
            __syncthreads();
        }
    }
    #pragma unroll
    for (int ni = 0; ni < 2; ++ni) {
        const int n = n0 + wn * 32 + ni * 16 + fr;
        const float bv = bias[n];
        #pragma unroll
        for (int mi = 0; mi < 2; ++mi) {
            #pragma unroll
            for (int q = 0; q < 4; ++q) {
                const int m = m0 + wm * 32 + mi * 16 + fg * 4 + q;
                const float v = acc[mi][ni][q] + bv;
                H[(size_t)m * 1024 + n] = f2bf(fmaxf(v, 0.f));
            }
        }
    }
}

// ---------------- K6: MFMA GEMM2 + bias + residual + LN2 -> f32 out ----------------
__global__ __launch_bounds__(256) void k_gemm2(
        const u16* __restrict__ A, const u16* __restrict__ Bw,
        const float* __restrict__ bias, const u16* __restrict__ resid,
        const float* __restrict__ lnw, const float* __restrict__ lnb,
        float* __restrict__ out) {
    __shared__ char smem[36864];
    u16* As = (u16*)smem;
    u16* Bs = (u16*)(smem + 4096);
    float* Y = (float*)smem;
    const int t = threadIdx.x;
    const int l = t & 63, w = t >> 6;
    const int m0 = blockIdx.x * 32;
    const int sAr = t >> 2, sc = t & 3;
    const int aslot = sAr * 32 + ((sc ^ ((sAr >> 1) & 3)) << 3);
    const u16* gA = A + (size_t)(m0 + sAr) * 1024 + sc * 8;
    const u16* gB[4];
    int bslot[4];
    #pragma unroll
    for (int i = 0; i < 4; ++i) {
        const int r = (t >> 2) + i * 64;
        gB[i] = Bw + (size_t)r * 1024 + sc * 8;
        bslot[i] = r * 32 + ((sc ^ ((r >> 1) & 3)) << 3);
    }
    const int fr = l & 15, fg = l >> 4;

    f32x4 acc[2][4];
    #pragma unroll
    for (int mi = 0; mi < 2; ++mi)
        #pragma unroll
        for (int ni = 0; ni < 4; ++ni)
            acc[mi][ni] = (f32x4){0.f, 0.f, 0.f, 0.f};

    if (t < 128) *(uint4*)&As[aslot] = *(const uint4*)(gA);
    #pragma unroll
    for (int i = 0; i < 4; ++i) *(uint4*)&Bs[bslot[i]] = *(const uint4*)(gB[i]);
    __syncthreads();

    for (int kt = 0; kt < 32; ++kt) {
        const int cur = kt & 1;
        uint4 na, nb[4];
        if (kt < 31) {
            if (t < 128) na = *(const uint4*)(gA + (kt + 1) * 32);
            #pragma unroll
            for (int i = 0; i < 4; ++i) nb[i] = *(const uint4*)(gB[i] + (kt + 1) * 32);
        }
        short8 af[2], bfr[4];
        #pragma unroll
        for (int mi = 0; mi < 2; ++mi) {
            const int r = mi * 16 + fr;
            af[mi] = *(const short8*)&As[cur * 1024 + r * 32 + ((fg ^ ((r >> 1) & 3)) << 3)];
        }
        #pragma unroll
        for (int ni = 0; ni < 4; ++ni) {
            const int r = w * 64 + ni * 16 + fr;
            bfr[ni] = *(const short8*)&Bs[cur * 8192 + r * 32 + ((fg ^ ((r >> 1) & 3)) << 3)];
        }
        #pragma unroll
        for (int mi = 0; mi < 2; ++mi)
            #pragma unroll
            for (int ni = 0; ni < 4; ++ni)
                acc[mi][ni] = __builtin_amdgcn_mfma_f32_16x16x32_bf16(af[mi], bfr[ni], acc[mi][ni], 0, 0, 0);
        if (kt < 31) {
            if (t < 128) *(uint4*)&As[(cur ^ 1) * 1024 + aslot] = na;
            #pragma unroll
            for (int i = 0; i < 4; ++i) *(uint4*)&Bs[(cur ^ 1) * 8192 + bslot[i]] = nb[i];
            __syncthreads();
        }
    }
    __syncthreads();
    #pragma unroll
    for (int ni = 0; ni < 4; ++ni) {
        const int n = w * 64 + ni * 16 + fr;
        const float bv = bias[n];
        #pragma unroll
        for (int mi = 0; mi < 2; ++mi) {
            #pragma unroll
            for (int q = 0; q < 4; ++q) {
                const int ml = mi * 16 + fg * 4 + q;
                Y[ml * 256 + n] = acc[mi][ni][q] + bv + bf2f(resid[(size_t)(m0 + ml) * 256 + n]);
            }
        }
    }
    __syncthreads();
    for (int rr = 0; rr < 8; ++rr) {
        const int m = w * 8 + rr;
        const float v0 = Y[m * 256 + l];
        const float v1 = Y[m * 256 + 64 + l];
        const float v2 = Y[m * 256 + 128 + l];
        const float v3 = Y[m * 256 + 192 + l];
        float s1 = v0 + v1 + v2 + v3;
        float s2 = v0 * v0 + v1 * v1 + v2 * v2 + v3 * v3;
        #pragma unroll
        for (int off = 32; off; off >>= 1) {
            s1 += __shfl_xor(s1, off);
            s2 += __shfl_xor(s2, off);
        }
        const float mean = s1 * (1.f / 256.f);
        const float var = s2 * (1.f / 256.f) - mean * mean;
        const float rs = rsqrtf(var + EPS_);
        const size_t ob = (size_t)(m0 + m) * 256;
        out[ob + l]        = (v0 - mean) * rs * lnw[l]        + lnb[l];
        out[ob + 64 + l]   = (v1 - mean) * rs * lnw[64 + l]   + lnb[64 + l];
        out[ob + 128 + l]  = (v2 - mean) * rs * lnw[128 + l]  + lnb[128 + l];
        out[ob + 192 + l]  = (v3 - mean) * rs * lnw[192 + l]  + lnb[192 + l];
    }
}

extern "C" void kernel_launch(void* const* d_in, const int* in_sizes, int n_in,
                              void* d_out, int out_size, void* d_ws, size_t ws_size,
                              hipStream_t stream) {
    const float* src  = (const float*)d_in[0];
    const float* pos  = (const float*)d_in[1];
    const float* refw = (const float*)d_in[4];
    const float* vpw  = (const float*)d_in[5];
    const float* vpb  = (const float*)d_in[6];
    const float* opw  = (const float*)d_in[7];
    const float* opb  = (const float*)d_in[8];
    const float* boxw = (const float*)d_in[9];
    const float* boxb = (const float*)d_in[10];
    const float* attw = (const float*)d_in[11];
    const float* attb = (const float*)d_in[12];
    const float* l1w  = (const float*)d_in[13];
    const float* l1b  = (const float*)d_in[14];
    const float* l2w  = (const float*)d_in[15];
    const float* l2b  = (const float*)d_in[16];
    const float* ln1w = (const float*)d_in[17];
    const float* ln1b = (const float*)d_in[18];
    const float* ln2w = (const float*)d_in[19];
    const float* ln2b = (const float*)d_in[20];

    // ws layout (89,128,960 B total — proven size):
    //  [0, 22282240)         vws bf16            -> after k_sample: l1wb/l2wb (1 MB)
    //  [22282240, 66846720)  logits f32 (44.6MB) -> after k_sample: src1b [22282240,44564480)
    //                                               + H half (44.6MB) at [44564480, 89128960)
    //  [66846720, 89128960)  SMP bf16            -> part of H overlay after k_oproj
    u16*   vws    = (u16*)d_ws;
    u16*   l1wb   = (u16*)d_ws;
    u16*   l2wb   = (u16*)((char*)d_ws + 524288);
    float* logits = (float*)((char*)d_ws + 22282240u);
    u16*   src1b  = (u16*)((char*)d_ws + 22282240u);
    u16*   Hbf    = (u16*)((char*)d_ws + 44564480u);
    u16*   smp    = (u16*)((char*)d_ws + 66846720u);

    hipLaunchKernelGGL(k_vprojm, dim3(680, 4), dim3(256), 0, stream, src, vpw, vpb, vws);
    hipLaunchKernelGGL(k_logits, dim3(680, 4), dim3(256), 0, stream,
                       src, pos, attw, attb, boxw, boxb, logits);
    hipLaunchKernelGGL(k_sample, dim3(5440), dim3(256), 0, stream, logits, refw, vws, smp);
    hipLaunchKernelGGL(k_cvt, dim3(256), dim3(256), 0, stream, l1w, l1wb, 65536);
    hipLaunchKernelGGL(k_cvt, dim3(256), dim3(256), 0, stream, l2w, l2wb, 65536);
    hipLaunchKernelGGL(k_oproj, dim3(1360), dim3(256), 0, stream,
                       smp, opw, opb, src, ln1w, ln1b, src1b);
    for (int h = 0; h < 2; ++h) {
        const u16* Ah = src1b + (size_t)h * MH_ * 256;
        float* outh   = (float*)d_out + (size_t)h * MH_ * 256;
        hipLaunchKernelGGL(k_gemm1, dim3(340, 16), dim3(256), 0, stream, Ah, l1wb, l1b, Hbf);
        hipLaunchKernelGGL(k_gemm2, dim3(680), dim3(256), 0, stream, Hbf, l2wb, l2b, Ah, ln2w, ln2b, outh);
    }
}

// Round 5
// 356.507 us; speedup vs baseline: 5.8758x; 1.0234x over previous
//
#include <hip/hip_runtime.h>
#include <stdint.h>

typedef unsigned short u16;
typedef __attribute__((ext_vector_type(8))) short short8;
typedef __attribute__((ext_vector_type(4))) float f32x4;

#define D_    256
#define NH_   8
#define HD_   32
#define LV_   21760
#define DFF_  1024
#define EPS_  1e-5f
#define MH_   21760   // rows per half (total M = 43520)
#define MT_   43520

__device__ __forceinline__ float bf2f(u16 u) {
    union { uint32_t i; float f; } x; x.i = ((uint32_t)u) << 16; return x.f;
}
__device__ __forceinline__ u16 f2bf(float f) {
    union { float f; uint32_t i; } x; x.f = f;
    uint32_t r = x.i + 0x7FFFu + ((x.i >> 16) & 1u);
    return (u16)(r >> 16);
}
__device__ __forceinline__ uint32_t pk2(float a, float b) {
    return (uint32_t)f2bf(a) | ((uint32_t)f2bf(b) << 16);
}
__device__ __forceinline__ float blo(uint32_t u) {
    union { uint32_t i; float f; } x; x.i = u << 16; return x.f;
}
__device__ __forceinline__ float bhi(uint32_t u) {
    union { uint32_t i; float f; } x; x.i = u & 0xffff0000u; return x.f;
}
__device__ __forceinline__ void cv8(u16* dst, float4 a, float4 b) {
    uint4 r;
    r.x = pk2(a.x, a.y); r.y = pk2(a.z, a.w);
    r.z = pk2(b.x, b.y); r.w = pk2(b.z, b.w);
    *(uint4*)dst = r;
}
__device__ __forceinline__ void cv8add(u16* dst, float4 a, float4 a2, float4 b, float4 b2) {
    uint4 r;
    r.x = pk2(a.x + a2.x, a.y + a2.y); r.y = pk2(a.z + a2.z, a.w + a2.w);
    r.z = pk2(b.x + b2.x, b.y + b2.y); r.w = pk2(b.z + b2.z, b.w + b2.w);
    *(uint4*)dst = r;
}

// ---------------- K0: f32 -> bf16 weight conversion ----------------
__global__ __launch_bounds__(256) void k_cvt(const float* __restrict__ in,
                                             u16* __restrict__ out, int n4) {
    int i = blockIdx.x * 256 + threadIdx.x;
    if (i < n4) {
        float4 v = ((const float4*)in)[i];
        uint2 r; r.x = pk2(v.x, v.y); r.y = pk2(v.z, v.w);
        *(uint2*)(out + (size_t)i * 4) = r;
    }
}

// ---------------- K1: MFMA value projection -> bf16 v[b,h,l,hd] ----------------
__global__ __launch_bounds__(256) void k_vprojm(
        const float* __restrict__ src, const float* __restrict__ vpw,
        const float* __restrict__ vpb, u16* __restrict__ vout) {
    __shared__ u16 As[2][64 * 32];
    __shared__ u16 Bs[2][64 * 32];
    const int t = threadIdx.x;
    const int l = t & 63, w = t >> 6;
    const int m0 = blockIdx.x * 64, n0 = blockIdx.y * 64;
    const int sr = t >> 2, sc = t & 3;
    const int wslot = sr * 32 + ((sc ^ ((sr >> 1) & 3)) << 3);
    const float* gA = src + (size_t)(m0 + sr) * 256 + sc * 8;
    const float* gB = vpw + (size_t)(n0 + sr) * 256 + sc * 8;
    const int fr = l & 15, fg = l >> 4;
    const int wm = w >> 1, wn = w & 1;

    f32x4 acc[2][2];
    #pragma unroll
    for (int mi = 0; mi < 2; ++mi)
        #pragma unroll
        for (int ni = 0; ni < 2; ++ni)
            acc[mi][ni] = (f32x4){0.f, 0.f, 0.f, 0.f};

    cv8(&As[0][wslot], *(const float4*)gA, *(const float4*)(gA + 4));
    cv8(&Bs[0][wslot], *(const float4*)gB, *(const float4*)(gB + 4));
    __syncthreads();

    for (int kt = 0; kt < 8; ++kt) {
        const int cur = kt & 1;
        float4 na0, na1, nb0, nb1;
        if (kt < 7) {
            na0 = *(const float4*)(gA + (kt + 1) * 32);
            na1 = *(const float4*)(gA + (kt + 1) * 32 + 4);
            nb0 = *(const float4*)(gB + (kt + 1) * 32);
            nb1 = *(const float4*)(gB + (kt + 1) * 32 + 4);
        }
        short8 af[2], bfr[2];
        #pragma unroll
        for (int mi = 0; mi < 2; ++mi) {
            const int r = wm * 32 + mi * 16 + fr;
            af[mi] = *(const short8*)&As[cur][r * 32 + ((fg ^ ((r >> 1) & 3)) << 3)];
        }
        #pragma unroll
        for (int ni = 0; ni < 2; ++ni) {
            const int r = wn * 32 + ni * 16 + fr;
            bfr[ni] = *(const short8*)&Bs[cur][r * 32 + ((fg ^ ((r >> 1) & 3)) << 3)];
        }
        #pragma unroll
        for (int mi = 0; mi < 2; ++mi)
            #pragma unroll
            for (int ni = 0; ni < 2; ++ni)
                acc[mi][ni] = __builtin_amdgcn_mfma_f32_16x16x32_bf16(af[mi], bfr[ni], acc[mi][ni], 0, 0, 0);
        if (kt < 7) {
            cv8(&As[cur ^ 1][wslot], na0, na1);
            cv8(&Bs[cur ^ 1][wslot], nb0, nb1);
            __syncthreads();
        }
    }
    const int b = m0 / LV_;          // 21760 % 64 == 0, no straddle
    #pragma unroll
    for (int ni = 0; ni < 2; ++ni) {
        const int n = n0 + wn * 32 + ni * 16 + fr;
        const float bv = vpb[n];
        const int h = n >> 5, hd = n & 31;
        #pragma unroll
        for (int mi = 0; mi < 2; ++mi) {
            #pragma unroll
            for (int q = 0; q < 4; ++q) {
                const int m = m0 + wm * 32 + mi * 16 + fg * 4 + q;
                const int lrow = m - b * LV_;
                vout[((size_t)(b * NH_ + h) * LV_ + lrow) * HD_ + hd] = f2bf(acc[mi][ni][q] + bv);
            }
        }
    }
}

// ---------------- K2: MFMA logits ----------------
__global__ __launch_bounds__(256) void k_logits(
        const float* __restrict__ src, const float* __restrict__ pos,
        const float* __restrict__ attw, const float* __restrict__ attb,
        const float* __restrict__ boxw, const float* __restrict__ boxb,
        float* __restrict__ logits) {
    __shared__ u16 As[2][64 * 32];
    __shared__ u16 Bs[2][64 * 32];
    const int t = threadIdx.x;
    const int l = t & 63, w = t >> 6;
    const int m0 = blockIdx.x * 64;
    const int n0g = blockIdx.y * 64;
    const float* Bsrc = (n0g < 128) ? (attw + (size_t)n0g * 256) : (boxw + (size_t)(n0g - 128) * 256);
    const float* bsrc = (n0g < 128) ? (attb + n0g) : (boxb + (n0g - 128));
    const int sr = t >> 2, sc = t & 3;
    const int wslot = sr * 32 + ((sc ^ ((sr >> 1) & 3)) << 3);
    const float* gAs = src + (size_t)(m0 + sr) * 256 + sc * 8;
    const float* gAp = pos + (size_t)(m0 + sr) * 256 + sc * 8;
    const float* gB  = Bsrc + (size_t)sr * 256 + sc * 8;
    const int fr = l & 15, fg = l >> 4;
    const int wm = w >> 1, wn = w & 1;

    f32x4 acc[2][2];
    #pragma unroll
    for (int mi = 0; mi < 2; ++mi)
        #pragma unroll
        for (int ni = 0; ni < 2; ++ni)
            acc[mi][ni] = (f32x4){0.f, 0.f, 0.f, 0.f};

    cv8add(&As[0][wslot], *(const float4*)gAs, *(const float4*)gAp,
                          *(const float4*)(gAs + 4), *(const float4*)(gAp + 4));
    cv8(&Bs[0][wslot], *(const float4*)gB, *(const float4*)(gB + 4));
    __syncthreads();

    for (int kt = 0; kt < 8; ++kt) {
        const int cur = kt & 1;
        float4 ns0, ns1, np0, np1, nb0, nb1;
        if (kt < 7) {
            ns0 = *(const float4*)(gAs + (kt + 1) * 32);
            ns1 = *(const float4*)(gAs + (kt + 1) * 32 + 4);
            np0 = *(const float4*)(gAp + (kt + 1) * 32);
            np1 = *(const float4*)(gAp + (kt + 1) * 32 + 4);
            nb0 = *(const float4*)(gB + (kt + 1) * 32);
            nb1 = *(const float4*)(gB + (kt + 1) * 32 + 4);
        }
        short8 af[2], bfr[2];
        #pragma unroll
        for (int mi = 0; mi < 2; ++mi) {
            const int r = wm * 32 + mi * 16 + fr;
            af[mi] = *(const short8*)&As[cur][r * 32 + ((fg ^ ((r >> 1) & 3)) << 3)];
        }
        #pragma unroll
        for (int ni = 0; ni < 2; ++ni) {
            const int r = wn * 32 + ni * 16 + fr;
            bfr[ni] = *(const short8*)&Bs[cur][r * 32 + ((fg ^ ((r >> 1) & 3)) << 3)];
        }
        #pragma unroll
        for (int mi = 0; mi < 2; ++mi)
            #pragma unroll
            for (int ni = 0; ni < 2; ++ni)
                acc[mi][ni] = __builtin_amdgcn_mfma_f32_16x16x32_bf16(af[mi], bfr[ni], acc[mi][ni], 0, 0, 0);
        if (kt < 7) {
            cv8add(&As[cur ^ 1][wslot], ns0, np0, ns1, np1);
            cv8(&Bs[cur ^ 1][wslot], nb0, nb1);
            __syncthreads();
        }
    }
    #pragma unroll
    for (int ni = 0; ni < 2; ++ni) {
        const int nl_ = wn * 32 + ni * 16 + fr;
        const float bv = bsrc[nl_];
        #pragma unroll
        for (int mi = 0; mi < 2; ++mi) {
            #pragma unroll
            for (int q = 0; q < 4; ++q) {
                const int m = m0 + wm * 32 + mi * 16 + fg * 4 + q;
                logits[(size_t)m * 256 + n0g + nl_] = acc[mi][ni][q] + bv;
            }
        }
    }
}

// ---------------- K3: sampling: softmax + grid + vectorized bilinear gather -> SMP bf16 ----------
// Gather: 8-lane groups, 4 hd (8 B) per lane, 4 rows in flight, 2 window iterations.
__global__ __launch_bounds__(256) void k_sample(
        const float* __restrict__ logits, const float* __restrict__ refw,
        const u16* __restrict__ vws, u16* __restrict__ smp) {
    __shared__ float AWL[8][128];
    __shared__ float OBL[8][128];
    __shared__ __align__(16) uint2 CWI[128 * 18];  // [u][rloc*4 + c4] pairs {f32 w bits, byte off}, stride 18
    __shared__ float RW[8][8];
    const int t = threadIdx.x;
    // bijective XCD swizzle (gridDim.x = 5440 = 8*680)
    const int bid = blockIdx.x;
    const int sb = (bid & 7) * (gridDim.x >> 3) + (bid >> 3);
    const long gr0 = (long)sb * 8;
    const int b = (int)(gr0 / LV_);
    {
        const float4* lp = (const float4*)(logits + gr0 * 256);
        #pragma unroll
        for (int i = 0; i < 2; ++i) {
            int ii = t + i * 256;
            float4 v = lp[ii];
            int r = ii >> 6, c4 = (ii & 63) << 2;
            if (c4 < 128) *(float4*)&AWL[r][c4] = v;
            else          *(float4*)&OBL[r][c4 - 128] = v;
        }
        if (t < 56) {
            int r2 = t / 7, k = t % 7;
            RW[r2][k] = refw[(gr0 + r2) * 7 + k];
        }
    }
    __syncthreads();
    if (t < 64) {
        const int r = t >> 3, h = t & 7;
        float* a = &AWL[r][h * 16];
        float m = a[0];
        #pragma unroll
        for (int k = 1; k < 16; ++k) m = fmaxf(m, a[k]);
        float s = 0.f;
        float e[16];
        #pragma unroll
        for (int k = 0; k < 16; ++k) { e[k] = __expf(a[k] - m); s += e[k]; }
        const float inv = 1.f / s;
        #pragma unroll
        for (int k = 0; k < 16; ++k) a[k] = e[k] * inv;
    }
    __syncthreads();

    const int e = t & 7;                 // lane in 8-lane group (hd = e*4 .. e*4+3)
    const int g = t >> 3;                // 0..31 groups
    const int rloc_g = g & 3, hg = g >> 2;
    const char* vbp = (const char*)vws +
        (((size_t)(b * NH_ + hg) * LV_) * HD_ + e * 4) * 2;
    const int cu = t & 127, rsel = t >> 7;
    const int ch = cu >> 4, cnl = (cu >> 2) & 3, cp = cu & 3;

    for (int wdw = 0; wdw < 2; ++wdw) {
        // ---- corner compute: 256 threads x 2 rows of this 4-row window ----
        #pragma unroll
        for (int rr = 0; rr < 2; ++rr) {
            const int rloc = rsel * 2 + rr;
            const int row = wdw * 4 + rloc;
            const float rw0 = RW[row][0], rw1 = RW[row][1], rw3 = RW[row][3], rw4 = RW[row][4], ang = RW[row][6];
            const int obb = ch * 16 + cnl * 4;
            const float ob0 = OBL[row][obb + 0];
            const float ob1 = OBL[row][obb + 1];
            const float ob2 = OBL[row][obb + 2];
            const float ob3 = OBL[row][obb + 3];
            const float cx = rw0 + ob0 * 0.125f * rw3;
            const float cy = rw1 + ob1 * 0.125f * rw4;
            const float bw = fmaxf(rw3 + ob2 * 0.125f * rw3, 0.f);
            const float bh = fmaxf(rw4 + ob3 * 0.125f * rw4, 0.f);
            const float kx = (cp & 1) ? 0.25f : -0.25f;
            const float ky = (cp >> 1) ? 0.25f : -0.25f;
            float sth, cth;
            __sincosf(ang, &sth, &cth);
            const float g0 = kx * bw, g1 = ky * bh;
            const float gx = cx + g0 * cth - g1 * sth;
            const float gy = cy + g0 * sth + g1 * cth;
            const int Wl = 128 >> cnl;
            const int st = (65536 - (65536 >> (2 * cnl))) / 3;
            const float x = gx * Wl - 0.5f, y = gy * Wl - 0.5f;
            const float xf = floorf(x), yf = floorf(y);
            const float wx = x - xf, wy = y - yf;
            const int x0 = (int)xf, y0 = (int)yf;
            const float awv = AWL[row][cu];
            uint2 cw[4];
            #pragma unroll
            for (int c4 = 0; c4 < 4; ++c4) {
                const int dx = c4 & 1, dy = c4 >> 1;
                const int xi = x0 + dx, yi = y0 + dy;
                const float wgt = (dx ? wx : 1.f - wx) * (dy ? wy : 1.f - wy);
                const bool valid = (xi >= 0) && (xi < Wl) && (yi >= 0) && (yi < Wl);
                const int xc = xi < 0 ? 0 : (xi > Wl - 1 ? Wl - 1 : xi);
                const int yc = yi < 0 ? 0 : (yi > Wl - 1 ? Wl - 1 : yi);
                const float wv = valid ? wgt * awv : 0.f;
                cw[c4].x = __float_as_uint(wv);
                cw[c4].y = (uint32_t)(st + yc * Wl + xc) * 64u;   // byte offset in v[b][h] plane
            }
            uint2* dst = &CWI[cu * 18 + rloc * 4];
            *(uint4*)(dst)     = *(const uint4*)&cw[0];
            *(uint4*)(dst + 2) = *(const uint4*)&cw[2];
        }
        __syncthreads();
        // ---- gather: group (rloc_g, hg), lane covers hd e*4..e*4+3 ----
        {
            const int row = wdw * 4 + rloc_g;
            float a0 = 0.f, a1 = 0.f, a2 = 0.f, a3 = 0.f;
            #pragma unroll 4
            for (int k = 0; k < 16; ++k) {
                const int ub = (hg * 16 + k) * 18 + rloc_g * 4;
                #pragma unroll
                for (int cc = 0; cc < 2; ++cc) {
                    const uint4 cw2 = *(const uint4*)&CWI[ub + cc * 2];
                    const float w0 = __uint_as_float(cw2.x);
                    const uint2 d0 = *(const uint2*)(vbp + cw2.y);
                    const float w1 = __uint_as_float(cw2.z);
                    const uint2 d1 = *(const uint2*)(vbp + cw2.w);
                    a0 += w0 * blo(d0.x); a1 += w0 * bhi(d0.x);
                    a2 += w0 * blo(d0.y); a3 += w0 * bhi(d0.y);
                    a0 += w1 * blo(d1.x); a1 += w1 * bhi(d1.x);
                    a2 += w1 * blo(d1.y); a3 += w1 * bhi(d1.y);
                }
            }
            uint2 o; o.x = pk2(a0, a1); o.y = pk2(a2, a3);
            *(uint2*)(smp + (size_t)(gr0 + row) * 256 + hg * 32 + e * 4) = o;
        }
        __syncthreads();   // protect CWI before next window overwrites
    }
}

// ---------------- K4: MFMA out-proj + residual(src f32) + LN1 -> src1b bf16 ----------------
__global__ __launch_bounds__(256) void k_oproj(
        const u16* __restrict__ A,
        const float* __restrict__ opw,
        const float* __restrict__ opb,
        const float* __restrict__ src,
        const float* __restrict__ lnw, const float* __restrict__ lnb,
        u16* __restrict__ out) {
    __shared__ char smem[36864];
    u16* As = (u16*)smem;
    u16* Bs = (u16*)(smem + 4096);
    float* Y = (float*)smem;
    const int t = threadIdx.x;
    const int l = t & 63, w = t >> 6;
    const int m0 = blockIdx.x * 32;
    const int sAr = t >> 2, sc = t & 3;
    const int aslot = sAr * 32 + ((sc ^ ((sAr >> 1) & 3)) << 3);
    const u16* gA = A + (size_t)(m0 + sAr) * 256 + sc * 8;
    const float* gB[4];
    int bslot[4];
    #pragma unroll
    for (int i = 0; i < 4; ++i) {
        const int r = (t >> 2) + i * 64;
        gB[i] = opw + (size_t)r * 256 + sc * 8;
        bslot[i] = r * 32 + ((sc ^ ((r >> 1) & 3)) << 3);
    }
    const int fr = l & 15, fg = l >> 4;

    f32x4 acc[2][4];
    #pragma unroll
    for (int mi = 0; mi < 2; ++mi)
        #pragma unroll
        for (int ni = 0; ni < 4; ++ni)
            acc[mi][ni] = (f32x4){0.f, 0.f, 0.f, 0.f};

    if (t < 128) *(uint4*)&As[aslot] = *(const uint4*)gA;
    #pragma unroll
    for (int i = 0; i < 4; ++i)
        cv8(&Bs[bslot[i]], *(const float4*)gB[i], *(const float4*)(gB[i] + 4));
    __syncthreads();

    for (int kt = 0; kt < 8; ++kt) {
        const int cur = kt & 1;
        uint4 na; float4 nb[4][2];
        if (kt < 7) {
            if (t < 128) na = *(const uint4*)(gA + (kt + 1) * 32);
            #pragma unroll
            for (int i = 0; i < 4; ++i) {
                nb[i][0] = *(const float4*)(gB[i] + (kt + 1) * 32);
                nb[i][1] = *(const float4*)(gB[i] + (kt + 1) * 32 + 4);
            }
        }
        short8 af[2], bfr[4];
        #pragma unroll
        for (int mi = 0; mi < 2; ++mi) {
            const int r = mi * 16 + fr;
            af[mi] = *(const short8*)&As[cur * 1024 + r * 32 + ((fg ^ ((r >> 1) & 3)) << 3)];
        }
        #pragma unroll
        for (int ni = 0; ni < 4; ++ni) {
            const int r = w * 64 + ni * 16 + fr;
            bfr[ni] = *(const short8*)&Bs[cur * 8192 + r * 32 + ((fg ^ ((r >> 1) & 3)) << 3)];
        }
        #pragma unroll
        for (int mi = 0; mi < 2; ++mi)
            #pragma unroll
            for (int ni = 0; ni < 4; ++ni)
                acc[mi][ni] = __builtin_amdgcn_mfma_f32_16x16x32_bf16(af[mi], bfr[ni], acc[mi][ni], 0, 0, 0);
        if (kt < 7) {
            if (t < 128) *(uint4*)&As[(cur ^ 1) * 1024 + aslot] = na;
            #pragma unroll
            for (int i = 0; i < 4; ++i)
                cv8(&Bs[(cur ^ 1) * 8192 + bslot[i]], nb[i][0], nb[i][1]);
            __syncthreads();
        }
    }
    __syncthreads();
    #pragma unroll
    for (int ni = 0; ni < 4; ++ni) {
        const int n = w * 64 + ni * 16 + fr;
        const float bv = opb[n];
        #pragma unroll
        for (int mi = 0; mi < 2; ++mi) {
            #pragma unroll
            for (int q = 0; q < 4; ++q) {
                const int ml = mi * 16 + fg * 4 + q;
                Y[ml * 256 + n] = acc[mi][ni][q] + bv + src[(size_t)(m0 + ml) * 256 + n];
            }
        }
    }
    __syncthreads();
    for (int rr = 0; rr < 8; ++rr) {
        const int m = w * 8 + rr;
        const float v0 = Y[m * 256 + l];
        const float v1 = Y[m * 256 + 64 + l];
        const float v2 = Y[m * 256 + 128 + l];
        const float v3 = Y[m * 256 + 192 + l];
        float s1 = v0 + v1 + v2 + v3;
        float s2 = v0 * v0 + v1 * v1 + v2 * v2 + v3 * v3;
        #pragma unroll
        for (int off = 32; off; off >>= 1) {
            s1 += __shfl_xor(s1, off);
            s2 += __shfl_xor(s2, off);
        }
        const float mean = s1 * (1.f / 256.f);
        const float var = s2 * (1.f / 256.f) - mean * mean;
        const float rs = rsqrtf(var + EPS_);
        const size_t ob = (size_t)(m0 + m) * 256;
        out[ob + l]       = f2bf((v0 - mean) * rs * lnw[l]       + lnb[l]);
        out[ob + 64 + l]  = f2bf((v1 - mean) * rs * lnw[64 + l]  + lnb[64 + l]);
        out[ob + 128 + l] = f2bf((v2 - mean) * rs * lnw[128 + l] + lnb[128 + l]);
        out[ob + 192 + l] = f2bf((v3 - mean) * rs * lnw[192 + l] + lnb[192 + l]);
    }
}

// ---------------- K5: MFMA GEMM1: H = relu(src1 @ l1w^T + b), 128x128 tile ----------------
// BM=BN=128 BK=32, 4 waves (2x2), each 64x64 (4x4 MFMA frags).
__global__ __launch_bounds__(256) void k_gemm1(
        const u16* __restrict__ A, const u16* __restrict__ Bw,
        const float* __restrict__ bias, u16* __restrict__ H) {
    __shared__ u16 As[2][128 * 32];
    __shared__ u16 Bs[2][128 * 32];
    const int t = threadIdx.x;
    const int l = t & 63, w = t >> 6;
    const int m0 = blockIdx.x * 128, n0 = blockIdx.y * 128;
    // staging: thread t -> row t>>1, chunks sc0=(2t)&3 and sc0+1 (16 consecutive elems)
    const int sr = t >> 1, sc0 = (t & 1) * 2;
    const int ws0 = sr * 32 + ((sc0 ^ ((sr >> 1) & 3)) << 3);
    const int ws1 = sr * 32 + (((sc0 + 1) ^ ((sr >> 1) & 3)) << 3);
    const u16* gA = A + (size_t)(m0 + sr) * 256 + sc0 * 8;
    const u16* gB = Bw + (size_t)(n0 + sr) * 256 + sc0 * 8;
    const int fr = l & 15, fg = l >> 4;
    const int wm = w >> 1, wn = w & 1;

    f32x4 acc[4][4];
    #pragma unroll
    for (int mi = 0; mi < 4; ++mi)
        #pragma unroll
        for (int ni = 0; ni < 4; ++ni)
            acc[mi][ni] = (f32x4){0.f, 0.f, 0.f, 0.f};

    *(uint4*)&As[0][ws0] = *(const uint4*)(gA);
    *(uint4*)&As[0][ws1] = *(const uint4*)(gA + 8);
    *(uint4*)&Bs[0][ws0] = *(const uint4*)(gB);
    *(uint4*)&Bs[0][ws1] = *(const uint4*)(gB + 8);
    __syncthreads();

    for (int kt = 0; kt < 8; ++kt) {
        const int cur = kt & 1;
        uint4 na0, na1, nb0, nb1;
        if (kt < 7) {
            na0 = *(const uint4*)(gA + (kt + 1) * 32);
            na1 = *(const uint4*)(gA + (kt + 1) * 32 + 8);
            nb0 = *(const uint4*)(gB + (kt + 1) * 32);
            nb1 = *(const uint4*)(gB + (kt + 1) * 32 + 8);
        }
        short8 af[4], bfr[4];
        #pragma unroll
        for (int mi = 0; mi < 4; ++mi) {
            const int r = wm * 64 + mi * 16 + fr;
            af[mi] = *(const short8*)&As[cur][r * 32 + ((fg ^ ((r >> 1) & 3)) << 3)];
        }
        #pragma unroll
        for (int ni = 0; ni < 4; ++ni) {
            const int r = wn * 64 + ni * 16 + fr;
            bfr[ni] = *(const short8*)&Bs[cur][r * 32 + ((fg ^ ((r >> 1) & 3)) << 3)];
        }
        #pragma unroll
        for (int mi = 0; mi < 4; ++mi)
            #pragma unroll
            for (int ni = 0; ni < 4; ++ni)
                acc[mi][ni] = __builtin_amdgcn_mfma_f32_16x16x32_bf16(af[mi], bfr[ni], acc[mi][ni], 0, 0, 0);
        if (kt < 7) {
            *(uint4*)&As[cur ^ 1][ws0] = na0;
            *(uint4*)&As[cur ^ 1][ws1] = na1;
            *(uint4*)&Bs[cur ^ 1][ws0] = nb0;
            *(uint4*)&Bs[cur ^ 1][ws1] = nb1;
            __syncthreads();
        }
    }
    #pragma unroll
    for (int ni = 0; ni < 4; ++ni) {
        const int n = n0 + wn * 64 + ni * 16 + fr;
        const float bv = bias[n];
        #pragma unroll
        for (int mi = 0; mi < 4; ++mi) {
            #pragma unroll
            for (int q = 0; q < 4; ++q) {
                const int m = m0 + wm * 64 + mi * 16 + fg * 4 + q;
                const float v = acc[mi][ni][q] + bv;
                H[(size_t)m * 1024 + n] = f2bf(fmaxf(v, 0.f));
            }
        }
    }
}

// ---------------- K6: MFMA GEMM2 + bias + residual + LN2 -> f32 out ----------------
__global__ __launch_bounds__(256) void k_gemm2(
        const u16* __restrict__ A, const u16* __restrict__ Bw,
        const float* __restrict__ bias, const u16* __restrict__ resid,
        const float* __restrict__ lnw, const float* __restrict__ lnb,
        float* __restrict__ out) {
    __shared__ char smem[36864];
    u16* As = (u16*)smem;
    u16* Bs = (u16*)(smem + 4096);
    float* Y = (float*)smem;
    const int t = threadIdx.x;
    const int l = t & 63, w = t >> 6;
    const int m0 = blockIdx.x * 32;
    const int sAr = t >> 2, sc = t & 3;
    const int aslot = sAr * 32 + ((sc ^ ((sAr >> 1) & 3)) << 3);
    const u16* gA = A + (size_t)(m0 + sAr) * 1024 + sc * 8;
    const u16* gB[4];
    int bslot[4];
    #pragma unroll
    for (int i = 0; i < 4; ++i) {
        const int r = (t >> 2) + i * 64;
        gB[i] = Bw + (size_t)r * 1024 + sc * 8;
        bslot[i] = r * 32 + ((sc ^ ((r >> 1) & 3)) << 3);
    }
    const int fr = l & 15, fg = l >> 4;

    f32x4 acc[2][4];
    #pragma unroll
    for (int mi = 0; mi < 2; ++mi)
        #pragma unroll
        for (int ni = 0; ni < 4; ++ni)
            acc[mi][ni] = (f32x4){0.f, 0.f, 0.f, 0.f};

    if (t < 128) *(uint4*)&As[aslot] = *(const uint4*)(gA);
    #pragma unroll
    for (int i = 0; i < 4; ++i) *(uint4*)&Bs[bslot[i]] = *(const uint4*)(gB[i]);
    __syncthreads();

    for (int kt = 0; kt < 32; ++kt) {
        const int cur = kt & 1;
        uint4 na, nb[4];
        if (kt < 31) {
            if (t < 128) na = *(const uint4*)(gA + (kt + 1) * 32);
            #pragma unroll
            for (int i = 0; i < 4; ++i) nb[i] = *(const uint4*)(gB[i] + (kt + 1) * 32);
        }
        short8 af[2], bfr[4];
        #pragma unroll
        for (int mi = 0; mi < 2; ++mi) {
            const int r = mi * 16 + fr;
            af[mi] = *(const short8*)&As[cur * 1024 + r * 32 + ((fg ^ ((r >> 1) & 3)) << 3)];
        }
        #pragma unroll
        for (int ni = 0; ni < 4; ++ni) {
            const int r = w * 64 + ni * 16 + fr;
            bfr[ni] = *(const short8*)&Bs[cur * 8192 + r * 32 + ((fg ^ ((r >> 1) & 3)) << 3)];
        }
        #pragma unroll
        for (int mi = 0; mi < 2; ++mi)
            #pragma unroll
            for (int ni = 0; ni < 4; ++ni)
                acc[mi][ni] = __builtin_amdgcn_mfma_f32_16x16x32_bf16(af[mi], bfr[ni], acc[mi][ni], 0, 0, 0);
        if (kt < 31) {
            if (t < 128) *(uint4*)&As[(cur ^ 1) * 1024 + aslot] = na;
            #pragma unroll
            for (int i = 0; i < 4; ++i) *(uint4*)&Bs[(cur ^ 1) * 8192 + bslot[i]] = nb[i];
            __syncthreads();
        }
    }
    __syncthreads();
    #pragma unroll
    for (int ni = 0; ni < 4; ++ni) {
        const int n = w * 64 + ni * 16 + fr;
        const float bv = bias[n];
        #pragma unroll
        for (int mi = 0; mi < 2; ++mi) {
            #pragma unroll
            for (int q = 0; q < 4; ++q) {
                const int ml = mi * 16 + fg * 4 + q;
                Y[ml * 256 + n] = acc[mi][ni][q] + bv + bf2f(resid[(size_t)(m0 + ml) * 256 + n]);
            }
        }
    }
    __syncthreads();
    for (int rr = 0; rr < 8; ++rr) {
        const int m = w * 8 + rr;
        const float v0 = Y[m * 256 + l];
        const float v1 = Y[m * 256 + 64 + l];
        const float v2 = Y[m * 256 + 128 + l];
        const float v3 = Y[m * 256 + 192 + l];
        float s1 = v0 + v1 + v2 + v3;
        float s2 = v0 * v0 + v1 * v1 + v2 * v2 + v3 * v3;
        #pragma unroll
        for (int off = 32; off; off >>= 1) {
            s1 += __shfl_xor(s1, off);
            s2 += __shfl_xor(s2, off);
        }
        const float mean = s1 * (1.f / 256.f);
        const float var = s2 * (1.f / 256.f) - mean * mean;
        const float rs = rsqrtf(var + EPS_);
        const size_t ob = (size_t)(m0 + m) * 256;
        out[ob + l]        = (v0 - mean) * rs * lnw[l]        + lnb[l];
        out[ob + 64 + l]   = (v1 - mean) * rs * lnw[64 + l]   + lnb[64 + l];
        out[ob + 128 + l]  = (v2 - mean) * rs * lnw[128 + l]  + lnb[128 + l];
        out[ob + 192 + l]  = (v3 - mean) * rs * lnw[192 + l]  + lnb[192 + l];
    }
}

extern "C" void kernel_launch(void* const* d_in, const int* in_sizes, int n_in,
                              void* d_out, int out_size, void* d_ws, size_t ws_size,
                              hipStream_t stream) {
    const float* src  = (const float*)d_in[0];
    const float* pos  = (const float*)d_in[1];
    const float* refw = (const float*)d_in[4];
    const float* vpw  = (const float*)d_in[5];
    const float* vpb  = (const float*)d_in[6];
    const float* opw  = (const float*)d_in[7];
    const float* opb  = (const float*)d_in[8];
    const float* boxw = (const float*)d_in[9];
    const float* boxb = (const float*)d_in[10];
    const float* attw = (const float*)d_in[11];
    const float* attb = (const float*)d_in[12];
    const float* l1w  = (const float*)d_in[13];
    const float* l1b  = (const float*)d_in[14];
    const float* l2w  = (const float*)d_in[15];
    const float* l2b  = (const float*)d_in[16];
    const float* ln1w = (const float*)d_in[17];
    const float* ln1b = (const float*)d_in[18];
    const float* ln2w = (const float*)d_in[19];
    const float* ln2b = (const float*)d_in[20];

    u16*   vws    = (u16*)d_ws;
    u16*   l1wb   = (u16*)d_ws;
    u16*   l2wb   = (u16*)((char*)d_ws + 524288);
    float* logits = (float*)((char*)d_ws + 22282240u);
    u16*   src1b  = (u16*)((char*)d_ws + 22282240u);
    u16*   Hbf    = (u16*)((char*)d_ws + 44564480u);
    u16*   smp    = (u16*)((char*)d_ws + 66846720u);

    hipLaunchKernelGGL(k_vprojm, dim3(680, 4), dim3(256), 0, stream, src, vpw, vpb, vws);
    hipLaunchKernelGGL(k_logits, dim3(680, 4), dim3(256), 0, stream,
                       src, pos, attw, attb, boxw, boxb, logits);
    hipLaunchKernelGGL(k_sample, dim3(5440), dim3(256), 0, stream, logits, refw, vws, smp);
    hipLaunchKernelGGL(k_cvt, dim3(256), dim3(256), 0, stream, l1w, l1wb, 65536);
    hipLaunchKernelGGL(k_cvt, dim3(256), dim3(256), 0, stream, l2w, l2wb, 65536);
    hipLaunchKernelGGL(k_oproj, dim3(1360), dim3(256), 0, stream,
                       smp, opw, opb, src, ln1w, ln1b, src1b);
    for (int h = 0; h < 2; ++h) {
        const u16* Ah = src1b + (size_t)h * MH_ * 256;
        float* outh   = (float*)d_out + (size_t)h * MH_ * 256;
        hipLaunchKernelGGL(k_gemm1, dim3(170, 8), dim3(256), 0, stream, Ah, l1wb, l1b, Hbf);
        hipLaunchKernelGGL(k_gemm2, dim3(680), dim3(256), 0, stream, Hbf, l2wb, l2b, Ah, ln2w, ln2b, outh);
    }
}

// Round 6
// 320.751 us; speedup vs baseline: 6.5308x; 1.1115x over previous
//
#include <hip/hip_runtime.h>
#include <stdint.h>

typedef unsigned short u16;
typedef __attribute__((ext_vector_type(8))) short short8;
typedef __attribute__((ext_vector_type(4))) float f32x4;

#define D_    256
#define NH_   8
#define HD_   32
#define LV_   21760
#define DFF_  1024
#define EPS_  1e-5f
#define MH_   21760   // rows per half (total M = 43520)
#define MT_   43520

__device__ __forceinline__ float bf2f(u16 u) {
    union { uint32_t i; float f; } x; x.i = ((uint32_t)u) << 16; return x.f;
}
__device__ __forceinline__ u16 f2bf(float f) {
    union { float f; uint32_t i; } x; x.f = f;
    uint32_t r = x.i + 0x7FFFu + ((x.i >> 16) & 1u);
    return (u16)(r >> 16);
}
__device__ __forceinline__ uint32_t pk2(float a, float b) {
    return (uint32_t)f2bf(a) | ((uint32_t)f2bf(b) << 16);
}
__device__ __forceinline__ float blo(uint32_t u) {
    union { uint32_t i; float f; } x; x.i = u << 16; return x.f;
}
__device__ __forceinline__ float bhi(uint32_t u) {
    union { uint32_t i; float f; } x; x.i = u & 0xffff0000u; return x.f;
}
__device__ __forceinline__ void cv8(u16* dst, float4 a, float4 b) {
    uint4 r;
    r.x = pk2(a.x, a.y); r.y = pk2(a.z, a.w);
    r.z = pk2(b.x, b.y); r.w = pk2(b.z, b.w);
    *(uint4*)dst = r;
}
__device__ __forceinline__ void cv8add(u16* dst, float4 a, float4 a2, float4 b, float4 b2) {
    uint4 r;
    r.x = pk2(a.x + a2.x, a.y + a2.y); r.y = pk2(a.z + a2.z, a.w + a2.w);
    r.z = pk2(b.x + b2.x, b.y + b2.y); r.w = pk2(b.z + b2.z, b.w + b2.w);
    *(uint4*)dst = r;
}

// ---------------- K0: f32 -> bf16 weight conversion ----------------
__global__ __launch_bounds__(256) void k_cvt(const float* __restrict__ in,
                                             u16* __restrict__ out, int n4) {
    int i = blockIdx.x * 256 + threadIdx.x;
    if (i < n4) {
        float4 v = ((const float4*)in)[i];
        uint2 r; r.x = pk2(v.x, v.y); r.y = pk2(v.z, v.w);
        *(uint2*)(out + (size_t)i * 4) = r;
    }
}

// ---------------- K1: MFMA value projection -> bf16 v[b,h,l,hd] ----------------
__global__ __launch_bounds__(256) void k_vprojm(
        const float* __restrict__ src, const float* __restrict__ vpw,
        const float* __restrict__ vpb, u16* __restrict__ vout) {
    __shared__ u16 As[2][64 * 32];
    __shared__ u16 Bs[2][64 * 32];
    const int t = threadIdx.x;
    const int l = t & 63, w = t >> 6;
    const int m0 = blockIdx.x * 64, n0 = blockIdx.y * 64;
    const int sr = t >> 2, sc = t & 3;
    const int wslot = sr * 32 + ((sc ^ ((sr >> 1) & 3)) << 3);
    const float* gA = src + (size_t)(m0 + sr) * 256 + sc * 8;
    const float* gB = vpw + (size_t)(n0 + sr) * 256 + sc * 8;
    const int fr = l & 15, fg = l >> 4;
    const int wm = w >> 1, wn = w & 1;

    f32x4 acc[2][2];
    #pragma unroll
    for (int mi = 0; mi < 2; ++mi)
        #pragma unroll
        for (int ni = 0; ni < 2; ++ni)
            acc[mi][ni] = (f32x4){0.f, 0.f, 0.f, 0.f};

    cv8(&As[0][wslot], *(const float4*)gA, *(const float4*)(gA + 4));
    cv8(&Bs[0][wslot], *(const float4*)gB, *(const float4*)(gB + 4));
    __syncthreads();

    for (int kt = 0; kt < 8; ++kt) {
        const int cur = kt & 1;
        float4 na0, na1, nb0, nb1;
        if (kt < 7) {
            na0 = *(const float4*)(gA + (kt + 1) * 32);
            na1 = *(const float4*)(gA + (kt + 1) * 32 + 4);
            nb0 = *(const float4*)(gB + (kt + 1) * 32);
            nb1 = *(const float4*)(gB + (kt + 1) * 32 + 4);
        }
        short8 af[2], bfr[2];
        #pragma unroll
        for (int mi = 0; mi < 2; ++mi) {
            const int r = wm * 32 + mi * 16 + fr;
            af[mi] = *(const short8*)&As[cur][r * 32 + ((fg ^ ((r >> 1) & 3)) << 3)];
        }
        #pragma unroll
        for (int ni = 0; ni < 2; ++ni) {
            const int r = wn * 32 + ni * 16 + fr;
            bfr[ni] = *(const short8*)&Bs[cur][r * 32 + ((fg ^ ((r >> 1) & 3)) << 3)];
        }
        #pragma unroll
        for (int mi = 0; mi < 2; ++mi)
            #pragma unroll
            for (int ni = 0; ni < 2; ++ni)
                acc[mi][ni] = __builtin_amdgcn_mfma_f32_16x16x32_bf16(af[mi], bfr[ni], acc[mi][ni], 0, 0, 0);
        if (kt < 7) {
            cv8(&As[cur ^ 1][wslot], na0, na1);
            cv8(&Bs[cur ^ 1][wslot], nb0, nb1);
            __syncthreads();
        }
    }
    const int b = m0 / LV_;          // 21760 % 64 == 0, no straddle
    #pragma unroll
    for (int ni = 0; ni < 2; ++ni) {
        const int n = n0 + wn * 32 + ni * 16 + fr;
        const float bv = vpb[n];
        const int h = n >> 5, hd = n & 31;
        #pragma unroll
        for (int mi = 0; mi < 2; ++mi) {
            #pragma unroll
            for (int q = 0; q < 4; ++q) {
                const int m = m0 + wm * 32 + mi * 16 + fg * 4 + q;
                const int lrow = m - b * LV_;
                vout[((size_t)(b * NH_ + h) * LV_ + lrow) * HD_ + hd] = f2bf(acc[mi][ni][q] + bv);
            }
        }
    }
}

// ---------------- K2: MFMA logits -> bf16 [M][head][att16|box16] ----------------
__global__ __launch_bounds__(256) void k_logits(
        const float* __restrict__ src, const float* __restrict__ pos,
        const float* __restrict__ attw, const float* __restrict__ attb,
        const float* __restrict__ boxw, const float* __restrict__ boxb,
        u16* __restrict__ lgout) {
    __shared__ u16 As[2][64 * 32];
    __shared__ u16 Bs[2][64 * 32];
    const int t = threadIdx.x;
    const int l = t & 63, w = t >> 6;
    const int m0 = blockIdx.x * 64;
    const int n0g = blockIdx.y * 64;
    const float* Bsrc = (n0g < 128) ? (attw + (size_t)n0g * 256) : (boxw + (size_t)(n0g - 128) * 256);
    const float* bsrc = (n0g < 128) ? (attb + n0g) : (boxb + (n0g - 128));
    const int sr = t >> 2, sc = t & 3;
    const int wslot = sr * 32 + ((sc ^ ((sr >> 1) & 3)) << 3);
    const float* gAs = src + (size_t)(m0 + sr) * 256 + sc * 8;
    const float* gAp = pos + (size_t)(m0 + sr) * 256 + sc * 8;
    const float* gB  = Bsrc + (size_t)sr * 256 + sc * 8;
    const int fr = l & 15, fg = l >> 4;
    const int wm = w >> 1, wn = w & 1;

    f32x4 acc[2][2];
    #pragma unroll
    for (int mi = 0; mi < 2; ++mi)
        #pragma unroll
        for (int ni = 0; ni < 2; ++ni)
            acc[mi][ni] = (f32x4){0.f, 0.f, 0.f, 0.f};

    cv8add(&As[0][wslot], *(const float4*)gAs, *(const float4*)gAp,
                          *(const float4*)(gAs + 4), *(const float4*)(gAp + 4));
    cv8(&Bs[0][wslot], *(const float4*)gB, *(const float4*)(gB + 4));
    __syncthreads();

    for (int kt = 0; kt < 8; ++kt) {
        const int cur = kt & 1;
        float4 ns0, ns1, np0, np1, nb0, nb1;
        if (kt < 7) {
            ns0 = *(const float4*)(gAs + (kt + 1) * 32);
            ns1 = *(const float4*)(gAs + (kt + 1) * 32 + 4);
            np0 = *(const float4*)(gAp + (kt + 1) * 32);
            np1 = *(const float4*)(gAp + (kt + 1) * 32 + 4);
            nb0 = *(const float4*)(gB + (kt + 1) * 32);
            nb1 = *(const float4*)(gB + (kt + 1) * 32 + 4);
        }
        short8 af[2], bfr[2];
        #pragma unroll
        for (int mi = 0; mi < 2; ++mi) {
            const int r = wm * 32 + mi * 16 + fr;
            af[mi] = *(const short8*)&As[cur][r * 32 + ((fg ^ ((r >> 1) & 3)) << 3)];
        }
        #pragma unroll
        for (int ni = 0; ni < 2; ++ni) {
            const int r = wn * 32 + ni * 16 + fr;
            bfr[ni] = *(const short8*)&Bs[cur][r * 32 + ((fg ^ ((r >> 1) & 3)) << 3)];
        }
        #pragma unroll
        for (int mi = 0; mi < 2; ++mi)
            #pragma unroll
            for (int ni = 0; ni < 2; ++ni)
                acc[mi][ni] = __builtin_amdgcn_mfma_f32_16x16x32_bf16(af[mi], bfr[ni], acc[mi][ni], 0, 0, 0);
        if (kt < 7) {
            cv8add(&As[cur ^ 1][wslot], ns0, np0, ns1, np1);
            cv8(&Bs[cur ^ 1][wslot], nb0, nb1);
            __syncthreads();
        }
    }
    #pragma unroll
    for (int ni = 0; ni < 2; ++ni) {
        const int nl_ = wn * 32 + ni * 16 + fr;
        const int n = n0g + nl_;
        const float bv = bsrc[nl_];
        // layout: [m][h*32 + (att? k : 16+k)], att n<128: h=n>>4,k=n&15; box: nb=n-128
        const int off = (n < 128) ? ((n >> 4) * 32 + (n & 15))
                                  : (((n - 128) >> 4) * 32 + 16 + ((n - 128) & 15));
        #pragma unroll
        for (int mi = 0; mi < 2; ++mi) {
            #pragma unroll
            for (int q = 0; q < 4; ++q) {
                const int m = m0 + wm * 32 + mi * 16 + fg * 4 + q;
                lgout[(size_t)m * 256 + off] = f2bf(acc[mi][ni][q] + bv);
            }
        }
    }
}

// ---------------- K3: sampling, (batch, head-pair)-split for L2 residency ----------------
// grid = 10880 = 8 combos x 1360 row-groups; combo = bid&7 -> pinned XCD.
// block: 16 rows x 2 heads; per-XCD gather working set = 2 v-planes = 2.78 MB < 4 MB L2.
__global__ __launch_bounds__(256) void k_sample(
        const u16* __restrict__ lg, const float* __restrict__ refw,
        const u16* __restrict__ vws, u16* __restrict__ smp) {
    __shared__ float LG[16][2][32];                 // [row][hsel][att16|box16]
    __shared__ float RW[16][8];
    __shared__ __align__(16) uint2 CWI[32 * 66];    // 32 (row,h) groups x 64 entries, stride 66
    const int t = threadIdx.x;
    const int bid = blockIdx.x;
    const int combo = bid & 7;            // -> XCD (round-robin dispatch)
    const int idx = bid >> 3;             // 0..1359
    const int b = combo >> 2, hp = combo & 3;
    const int h0 = hp * 2;
    const long gr0 = (long)b * LV_ + (long)idx * 16;

    // ---- stage logits slice (bf16 -> f32) + refw ----
    {
        const int row = t >> 4, part = t & 15;      // 16 parts x 4 vals = 64 per row
        const uint2 v = *(const uint2*)(lg + (size_t)(gr0 + row) * 256 + h0 * 32 + part * 4);
        const int hs = part >> 3, kk = (part & 7) * 4;
        LG[row][hs][kk]     = blo(v.x);
        LG[row][hs][kk + 1] = bhi(v.x);
        LG[row][hs][kk + 2] = blo(v.y);
        LG[row][hs][kk + 3] = bhi(v.y);
        if (t < 112) {
            int r2 = t / 7, k = t % 7;
            RW[r2][k] = refw[(gr0 + r2) * 7 + k];
        }
    }
    __syncthreads();
    // ---- softmax over 16 att values per (row, head) ----
    if (t < 32) {
        const int row = t >> 1, hs = t & 1;
        float* a = LG[row][hs];
        float m = a[0];
        #pragma unroll
        for (int k = 1; k < 16; ++k) m = fmaxf(m, a[k]);
        float s = 0.f;
        float e[16];
        #pragma unroll
        for (int k = 0; k < 16; ++k) { e[k] = __expf(a[k] - m); s += e[k]; }
        const float inv = 1.f / s;
        #pragma unroll
        for (int k = 0; k < 16; ++k) a[k] = e[k] * inv;
    }
    __syncthreads();
    // ---- corner compute: 512 units = (16 rows x 2 hs x 4 nl x 4 p), 2 per thread ----
    #pragma unroll
    for (int uu = 0; uu < 2; ++uu) {
        const int u = t + uu * 256;
        const int row = u >> 5, rem = u & 31;
        const int hs = rem >> 4, nl = (rem >> 2) & 3, p = rem & 3;
        const float rw0 = RW[row][0], rw1 = RW[row][1], rw3 = RW[row][3], rw4 = RW[row][4], ang = RW[row][6];
        const float ob0 = LG[row][hs][16 + nl * 4 + 0];
        const float ob1 = LG[row][hs][16 + nl * 4 + 1];
        const float ob2 = LG[row][hs][16 + nl * 4 + 2];
        const float ob3 = LG[row][hs][16 + nl * 4 + 3];
        const float cx = rw0 + ob0 * 0.125f * rw3;
        const float cy = rw1 + ob1 * 0.125f * rw4;
        const float bw = fmaxf(rw3 + ob2 * 0.125f * rw3, 0.f);
        const float bh = fmaxf(rw4 + ob3 * 0.125f * rw4, 0.f);
        const float kx = (p & 1) ? 0.25f : -0.25f;
        const float ky = (p >> 1) ? 0.25f : -0.25f;
        float sth, cth;
        __sincosf(ang, &sth, &cth);
        const float g0 = kx * bw, g1 = ky * bh;
        const float gx = cx + g0 * cth - g1 * sth;
        const float gy = cy + g0 * sth + g1 * cth;
        const int Wl = 128 >> nl;
        const int st = (65536 - (65536 >> (2 * nl))) / 3;
        const float x = gx * Wl - 0.5f, y = gy * Wl - 0.5f;
        const float xf = floorf(x), yf = floorf(y);
        const float wx = x - xf, wy = y - yf;
        const int x0 = (int)xf, y0 = (int)yf;
        const float awv = LG[row][hs][nl * 4 + p];
        uint2 cw[4];
        #pragma unroll
        for (int c4 = 0; c4 < 4; ++c4) {
            const int dx = c4 & 1, dy = c4 >> 1;
            const int xi = x0 + dx, yi = y0 + dy;
            const float wgt = (dx ? wx : 1.f - wx) * (dy ? wy : 1.f - wy);
            const bool valid = (xi >= 0) && (xi < Wl) && (yi >= 0) && (yi < Wl);
            const int xc = xi < 0 ? 0 : (xi > Wl - 1 ? Wl - 1 : xi);
            const int yc = yi < 0 ? 0 : (yi > Wl - 1 ? Wl - 1 : yi);
            const float wv = valid ? wgt * awv : 0.f;
            cw[c4].x = __float_as_uint(wv);
            cw[c4].y = (uint32_t)(st + yc * Wl + xc) * 64u;   // byte offset in v[b][h] plane
        }
        uint2* dst = &CWI[(row * 2 + hs) * 66 + (nl * 4 + p) * 4];
        *(uint4*)(dst)     = *(const uint4*)&cw[0];
        *(uint4*)(dst + 2) = *(const uint4*)&cw[2];
    }
    __syncthreads();
    // ---- gather: group g=(row,hs), lane e covers hd e*4..e*4+3 ----
    {
        const int e = t & 7, g = t >> 3;
        const int row = g >> 1, hs = g & 1, h = h0 + hs;
        const char* vbp = (const char*)vws +
            (((size_t)(b * NH_ + h) * LV_) * HD_ + e * 4) * 2;
        const uint2* cbase = &CWI[g * 66];
        float a0 = 0.f, a1 = 0.f, a2 = 0.f, a3 = 0.f;
        #pragma unroll 4
        for (int k = 0; k < 16; ++k) {
            #pragma unroll
            for (int cc = 0; cc < 2; ++cc) {
                const uint4 cw2 = *(const uint4*)&cbase[k * 4 + cc * 2];
                const float w0 = __uint_as_float(cw2.x);
                const uint2 d0 = *(const uint2*)(vbp + cw2.y);
                const float w1 = __uint_as_float(cw2.z);
                const uint2 d1 = *(const uint2*)(vbp + cw2.w);
                a0 += w0 * blo(d0.x); a1 += w0 * bhi(d0.x);
                a2 += w0 * blo(d0.y); a3 += w0 * bhi(d0.y);
                a0 += w1 * blo(d1.x); a1 += w1 * bhi(d1.x);
                a2 += w1 * blo(d1.y); a3 += w1 * bhi(d1.y);
            }
        }
        uint2 o; o.x = pk2(a0, a1); o.y = pk2(a2, a3);
        *(uint2*)(smp + (size_t)(gr0 + row) * 256 + h * 32 + e * 4) = o;
    }
}

// ---------------- K4: MFMA out-proj + residual(src f32) + LN1 -> src1b bf16 ----------------
__global__ __launch_bounds__(256) void k_oproj(
        const u16* __restrict__ A,
        const float* __restrict__ opw,
        const float* __restrict__ opb,
        const float* __restrict__ src,
        const float* __restrict__ lnw, const float* __restrict__ lnb,
        u16* __restrict__ out) {
    __shared__ char smem[36864];
    u16* As = (u16*)smem;
    u16* Bs = (u16*)(smem + 4096);
    float* Y = (float*)smem;
    const int t = threadIdx.x;
    const int l = t & 63, w = t >> 6;
    const int m0 = blockIdx.x * 32;
    const int sAr = t >> 2, sc = t & 3;
    const int aslot = sAr * 32 + ((sc ^ ((sAr >> 1) & 3)) << 3);
    const u16* gA = A + (size_t)(m0 + sAr) * 256 + sc * 8;
    const float* gB[4];
    int bslot[4];
    #pragma unroll
    for (int i = 0; i < 4; ++i) {
        const int r = (t >> 2) + i * 64;
        gB[i] = opw + (size_t)r * 256 + sc * 8;
        bslot[i] = r * 32 + ((sc ^ ((r >> 1) & 3)) << 3);
    }
    const int fr = l & 15, fg = l >> 4;

    f32x4 acc[2][4];
    #pragma unroll
    for (int mi = 0; mi < 2; ++mi)
        #pragma unroll
        for (int ni = 0; ni < 4; ++ni)
            acc[mi][ni] = (f32x4){0.f, 0.f, 0.f, 0.f};

    if (t < 128) *(uint4*)&As[aslot] = *(const uint4*)gA;
    #pragma unroll
    for (int i = 0; i < 4; ++i)
        cv8(&Bs[bslot[i]], *(const float4*)gB[i], *(const float4*)(gB[i] + 4));
    __syncthreads();

    for (int kt = 0; kt < 8; ++kt) {
        const int cur = kt & 1;
        uint4 na; float4 nb[4][2];
        if (kt < 7) {
            if (t < 128) na = *(const uint4*)(gA + (kt + 1) * 32);
            #pragma unroll
            for (int i = 0; i < 4; ++i) {
                nb[i][0] = *(const float4*)(gB[i] + (kt + 1) * 32);
                nb[i][1] = *(const float4*)(gB[i] + (kt + 1) * 32 + 4);
            }
        }
        short8 af[2], bfr[4];
        #pragma unroll
        for (int mi = 0; mi < 2; ++mi) {
            const int r = mi * 16 + fr;
            af[mi] = *(const short8*)&As[cur * 1024 + r * 32 + ((fg ^ ((r >> 1) & 3)) << 3)];
        }
        #pragma unroll
        for (int ni = 0; ni < 4; ++ni) {
            const int r = w * 64 + ni * 16 + fr;
            bfr[ni] = *(const short8*)&Bs[cur * 8192 + r * 32 + ((fg ^ ((r >> 1) & 3)) << 3)];
        }
        #pragma unroll
        for (int mi = 0; mi < 2; ++mi)
            #pragma unroll
            for (int ni = 0; ni < 4; ++ni)
                acc[mi][ni] = __builtin_amdgcn_mfma_f32_16x16x32_bf16(af[mi], bfr[ni], acc[mi][ni], 0, 0, 0);
        if (kt < 7) {
            if (t < 128) *(uint4*)&As[(cur ^ 1) * 1024 + aslot] = na;
            #pragma unroll
            for (int i = 0; i < 4; ++i)
                cv8(&Bs[(cur ^ 1) * 8192 + bslot[i]], nb[i][0], nb[i][1]);
            __syncthreads();
        }
    }
    __syncthreads();
    #pragma unroll
    for (int ni = 0; ni < 4; ++ni) {
        const int n = w * 64 + ni * 16 + fr;
        const float bv = opb[n];
        #pragma unroll
        for (int mi = 0; mi < 2; ++mi) {
            #pragma unroll
            for (int q = 0; q < 4; ++q) {
                const int ml = mi * 16 + fg * 4 + q;
                Y[ml * 256 + n] = acc[mi][ni][q] + bv + src[(size_t)(m0 + ml) * 256 + n];
            }
        }
    }
    __syncthreads();
    for (int rr = 0; rr < 8; ++rr) {
        const int m = w * 8 + rr;
        const float v0 = Y[m * 256 + l];
        const float v1 = Y[m * 256 + 64 + l];
        const float v2 = Y[m * 256 + 128 + l];
        const float v3 = Y[m * 256 + 192 + l];
        float s1 = v0 + v1 + v2 + v3;
        float s2 = v0 * v0 + v1 * v1 + v2 * v2 + v3 * v3;
        #pragma unroll
        for (int off = 32; off; off >>= 1) {
            s1 += __shfl_xor(s1, off);
            s2 += __shfl_xor(s2, off);
        }
        const float mean = s1 * (1.f / 256.f);
        const float var = s2 * (1.f / 256.f) - mean * mean;
        const float rs = rsqrtf(var + EPS_);
        const size_t ob = (size_t)(m0 + m) * 256;
        out[ob + l]       = f2bf((v0 - mean) * rs * lnw[l]       + lnb[l]);
        out[ob + 64 + l]  = f2bf((v1 - mean) * rs * lnw[64 + l]  + lnb[64 + l]);
        out[ob + 128 + l] = f2bf((v2 - mean) * rs * lnw[128 + l] + lnb[128 + l]);
        out[ob + 192 + l] = f2bf((v3 - mean) * rs * lnw[192 + l] + lnb[192 + l]);
    }
}

// ---------------- K5: MFMA GEMM1: H = relu(src1 @ l1w^T + b), 128x128 tile ----------------
__global__ __launch_bounds__(256) void k_gemm1(
        const u16* __restrict__ A, const u16* __restrict__ Bw,
        const float* __restrict__ bias, u16* __restrict__ H) {
    __shared__ u16 As[2][128 * 32];
    __shared__ u16 Bs[2][128 * 32];
    const int t = threadIdx.x;
    const int l = t & 63, w = t >> 6;
    const int m0 = blockIdx.x * 128, n0 = blockIdx.y * 128;
    const int sr = t >> 1, sc0 = (t & 1) * 2;
    const int ws0 = sr * 32 + ((sc0 ^ ((sr >> 1) & 3)) << 3);
    const int ws1 = sr * 32 + (((sc0 + 1) ^ ((sr >> 1) & 3)) << 3);
    const u16* gA = A + (size_t)(m0 + sr) * 256 + sc0 * 8;
    const u16* gB = Bw + (size_t)(n0 + sr) * 256 + sc0 * 8;
    const int fr = l & 15, fg = l >> 4;
    const int wm = w >> 1, wn = w & 1;

    f32x4 acc[4][4];
    #pragma unroll
    for (int mi = 0; mi < 4; ++mi)
        #pragma unroll
        for (int ni = 0; ni < 4; ++ni)
            acc[mi][ni] = (f32x4){0.f, 0.f, 0.f, 0.f};

    *(uint4*)&As[0][ws0] = *(const uint4*)(gA);
    *(uint4*)&As[0][ws1] = *(const uint4*)(gA + 8);
    *(uint4*)&Bs[0][ws0] = *(const uint4*)(gB);
    *(uint4*)&Bs[0][ws1] = *(const uint4*)(gB + 8);
    __syncthreads();

    for (int kt = 0; kt < 8; ++kt) {
        const int cur = kt & 1;
        uint4 na0, na1, nb0, nb1;
        if (kt < 7) {
            na0 = *(const uint4*)(gA + (kt + 1) * 32);
            na1 = *(const uint4*)(gA + (kt + 1) * 32 + 8);
            nb0 = *(const uint4*)(gB + (kt + 1) * 32);
            nb1 = *(const uint4*)(gB + (kt + 1) * 32 + 8);
        }
        short8 af[4], bfr[4];
        #pragma unroll
        for (int mi = 0; mi < 4; ++mi) {
            const int r = wm * 64 + mi * 16 + fr;
            af[mi] = *(const short8*)&As[cur][r * 32 + ((fg ^ ((r >> 1) & 3)) << 3)];
        }
        #pragma unroll
        for (int ni = 0; ni < 4; ++ni) {
            const int r = wn * 64 + ni * 16 + fr;
            bfr[ni] = *(const short8*)&Bs[cur][r * 32 + ((fg ^ ((r >> 1) & 3)) << 3)];
        }
        #pragma unroll
        for (int mi = 0; mi < 4; ++mi)
            #pragma unroll
            for (int ni = 0; ni < 4; ++ni)
                acc[mi][ni] = __builtin_amdgcn_mfma_f32_16x16x32_bf16(af[mi], bfr[ni], acc[mi][ni], 0, 0, 0);
        if (kt < 7) {
            *(uint4*)&As[cur ^ 1][ws0] = na0;
            *(uint4*)&As[cur ^ 1][ws1] = na1;
            *(uint4*)&Bs[cur ^ 1][ws0] = nb0;
            *(uint4*)&Bs[cur ^ 1][ws1] = nb1;
            __syncthreads();
        }
    }
    #pragma unroll
    for (int ni = 0; ni < 4; ++ni) {
        const int n = n0 + wn * 64 + ni * 16 + fr;
        const float bv = bias[n];
        #pragma unroll
        for (int mi = 0; mi < 4; ++mi) {
            #pragma unroll
            for (int q = 0; q < 4; ++q) {
                const int m = m0 + wm * 64 + mi * 16 + fg * 4 + q;
                const float v = acc[mi][ni][q] + bv;
                H[(size_t)m * 1024 + n] = f2bf(fmaxf(v, 0.f));
            }
        }
    }
}

// ---------------- K6: MFMA GEMM2 + bias + residual + LN2 -> f32 out ----------------
__global__ __launch_bounds__(256) void k_gemm2(
        const u16* __restrict__ A, const u16* __restrict__ Bw,
        const float* __restrict__ bias, const u16* __restrict__ resid,
        const float* __restrict__ lnw, const float* __restrict__ lnb,
        float* __restrict__ out) {
    __shared__ char smem[36864];
    u16* As = (u16*)smem;
    u16* Bs = (u16*)(smem + 4096);
    float* Y = (float*)smem;
    const int t = threadIdx.x;
    const int l = t & 63, w = t >> 6;
    const int m0 = blockIdx.x * 32;
    const int sAr = t >> 2, sc = t & 3;
    const int aslot = sAr * 32 + ((sc ^ ((sAr >> 1) & 3)) << 3);
    const u16* gA = A + (size_t)(m0 + sAr) * 1024 + sc * 8;
    const u16* gB[4];
    int bslot[4];
    #pragma unroll
    for (int i = 0; i < 4; ++i) {
        const int r = (t >> 2) + i * 64;
        gB[i] = Bw + (size_t)r * 1024 + sc * 8;
        bslot[i] = r * 32 + ((sc ^ ((r >> 1) & 3)) << 3);
    }
    const int fr = l & 15, fg = l >> 4;

    f32x4 acc[2][4];
    #pragma unroll
    for (int mi = 0; mi < 2; ++mi)
        #pragma unroll
        for (int ni = 0; ni < 4; ++ni)
            acc[mi][ni] = (f32x4){0.f, 0.f, 0.f, 0.f};

    if (t < 128) *(uint4*)&As[aslot] = *(const uint4*)(gA);
    #pragma unroll
    for (int i = 0; i < 4; ++i) *(uint4*)&Bs[bslot[i]] = *(const uint4*)(gB[i]);
    __syncthreads();

    for (int kt = 0; kt < 32; ++kt) {
        const int cur = kt & 1;
        uint4 na, nb[4];
        if (kt < 31) {
            if (t < 128) na = *(const uint4*)(gA + (kt + 1) * 32);
            #pragma unroll
            for (int i = 0; i < 4; ++i) nb[i] = *(const uint4*)(gB[i] + (kt + 1) * 32);
        }
        short8 af[2], bfr[4];
        #pragma unroll
        for (int mi = 0; mi < 2; ++mi) {
            const int r = mi * 16 + fr;
            af[mi] = *(const short8*)&As[cur * 1024 + r * 32 + ((fg ^ ((r >> 1) & 3)) << 3)];
        }
        #pragma unroll
        for (int ni = 0; ni < 4; ++ni) {
            const int r = w * 64 + ni * 16 + fr;
            bfr[ni] = *(const short8*)&Bs[cur * 8192 + r * 32 + ((fg ^ ((r >> 1) & 3)) << 3)];
        }
        #pragma unroll
        for (int mi = 0; mi < 2; ++mi)
            #pragma unroll
            for (int ni = 0; ni < 4; ++ni)
                acc[mi][ni] = __builtin_amdgcn_mfma_f32_16x16x32_bf16(af[mi], bfr[ni], acc[mi][ni], 0, 0, 0);
        if (kt < 31) {
            if (t < 128) *(uint4*)&As[(cur ^ 1) * 1024 + aslot] = na;
            #pragma unroll
            for (int i = 0; i < 4; ++i) *(uint4*)&Bs[(cur ^ 1) * 8192 + bslot[i]] = nb[i];
            __syncthreads();
        }
    }
    __syncthreads();
    #pragma unroll
    for (int ni = 0; ni < 4; ++ni) {
        const int n = w * 64 + ni * 16 + fr;
        const float bv = bias[n];
        #pragma unroll
        for (int mi = 0; mi < 2; ++mi) {
            #pragma unroll
            for (int q = 0; q < 4; ++q) {
                const int ml = mi * 16 + fg * 4 + q;
                Y[ml * 256 + n] = acc[mi][ni][q] + bv + bf2f(resid[(size_t)(m0 + ml) * 256 + n]);
            }
        }
    }
    __syncthreads();
    for (int rr = 0; rr < 8; ++rr) {
        const int m = w * 8 + rr;
        const float v0 = Y[m * 256 + l];
        const float v1 = Y[m * 256 + 64 + l];
        const float v2 = Y[m * 256 + 128 + l];
        const float v3 = Y[m * 256 + 192 + l];
        float s1 = v0 + v1 + v2 + v3;
        float s2 = v0 * v0 + v1 * v1 + v2 * v2 + v3 * v3;
        #pragma unroll
        for (int off = 32; off; off >>= 1) {
            s1 += __shfl_xor(s1, off);
            s2 += __shfl_xor(s2, off);
        }
        const float mean = s1 * (1.f / 256.f);
        const float var = s2 * (1.f / 256.f) - mean * mean;
        const float rs = rsqrtf(var + EPS_);
        const size_t ob = (size_t)(m0 + m) * 256;
        out[ob + l]        = (v0 - mean) * rs * lnw[l]        + lnb[l];
        out[ob + 64 + l]   = (v1 - mean) * rs * lnw[64 + l]   + lnb[64 + l];
        out[ob + 128 + l]  = (v2 - mean) * rs * lnw[128 + l]  + lnb[128 + l];
        out[ob + 192 + l]  = (v3 - mean) * rs * lnw[192 + l]  + lnb[192 + l];
    }
}

extern "C" void kernel_launch(void* const* d_in, const int* in_sizes, int n_in,
                              void* d_out, int out_size, void* d_ws, size_t ws_size,
                              hipStream_t stream) {
    const float* src  = (const float*)d_in[0];
    const float* pos  = (const float*)d_in[1];
    const float* refw = (const float*)d_in[4];
    const float* vpw  = (const float*)d_in[5];
    const float* vpb  = (const float*)d_in[6];
    const float* opw  = (const float*)d_in[7];
    const float* opb  = (const float*)d_in[8];
    const float* boxw = (const float*)d_in[9];
    const float* boxb = (const float*)d_in[10];
    const float* attw = (const float*)d_in[11];
    const float* attb = (const float*)d_in[12];
    const float* l1w  = (const float*)d_in[13];
    const float* l1b  = (const float*)d_in[14];
    const float* l2w  = (const float*)d_in[15];
    const float* l2b  = (const float*)d_in[16];
    const float* ln1w = (const float*)d_in[17];
    const float* ln1b = (const float*)d_in[18];
    const float* ln2w = (const float*)d_in[19];
    const float* ln2b = (const float*)d_in[20];

    // ws layout (89,128,960 B total):
    //  [0, 22282240)         vws bf16            -> after k_sample: l1wb/l2wb (1 MB)
    //  [22282240, 44564480)  logits bf16 (22.3MB)-> after k_sample: src1b (bf16)
    //  [44564480, 89128960)  H half (bf16)       ; smp bf16 at [66846720, 89128960)
    u16*   vws    = (u16*)d_ws;
    u16*   l1wb   = (u16*)d_ws;
    u16*   l2wb   = (u16*)((char*)d_ws + 524288);
    u16*   logitsb= (u16*)((char*)d_ws + 22282240u);
    u16*   src1b  = (u16*)((char*)d_ws + 22282240u);
    u16*   Hbf    = (u16*)((char*)d_ws + 44564480u);
    u16*   smp    = (u16*)((char*)d_ws + 66846720u);

    hipLaunchKernelGGL(k_vprojm, dim3(680, 4), dim3(256), 0, stream, src, vpw, vpb, vws);
    hipLaunchKernelGGL(k_logits, dim3(680, 4), dim3(256), 0, stream,
                       src, pos, attw, attb, boxw, boxb, logitsb);
    hipLaunchKernelGGL(k_sample, dim3(10880), dim3(256), 0, stream, logitsb, refw, vws, smp);
    hipLaunchKernelGGL(k_cvt, dim3(256), dim3(256), 0, stream, l1w, l1wb, 65536);
    hipLaunchKernelGGL(k_cvt, dim3(256), dim3(256), 0, stream, l2w, l2wb, 65536);
    hipLaunchKernelGGL(k_oproj, dim3(1360), dim3(256), 0, stream,
                       smp, opw, opb, src, ln1w, ln1b, src1b);
    for (int h = 0; h < 2; ++h) {
        const u16* Ah = src1b + (size_t)h * MH_ * 256;
        float* outh   = (float*)d_out + (size_t)h * MH_ * 256;
        hipLaunchKernelGGL(k_gemm1, dim3(170, 8), dim3(256), 0, stream, Ah, l1wb, l1b, Hbf);
        hipLaunchKernelGGL(k_gemm2, dim3(680), dim3(256), 0, stream, Hbf, l2wb, l2b, Ah, ln2w, ln2b, outh);
    }
}